// Round 1
// baseline (17305.183 us; speedup 1.0000x reference)
//
#include <hip/hip_runtime.h>

// Problem constants (from reference)
constexpr int NN = 1000000;   // nodes
constexpr int EE = 32000000;  // edges
constexpr int KK = 3;         // stacks
constexpr int TT = 4;         // layers

// ---------------- degree: deg[c] += w[e] ----------------
__global__ void deg_kernel(const int* __restrict__ col, const float* __restrict__ w,
                           float* __restrict__ deg, int E) {
    int stride = gridDim.x * blockDim.x;
    for (int e = blockIdx.x * blockDim.x + threadIdx.x; e < E; e += stride)
        atomicAdd(&deg[col[e]], w[e]);
}

// ---------------- dinv = deg>0 ? rsqrt(deg) : 0 (in place) ----------------
__global__ void dinv_kernel(float* __restrict__ deg, int n) {
    int i = blockIdx.x * blockDim.x + threadIdx.x;
    if (i < n) {
        float d = deg[i];
        deg[i] = (d > 0.f) ? rsqrtf(d) : 0.f;
    }
}

// ---------------- layer-0 scalar SpMV: y[c] += norm_e * x[r] ----------------
__global__ void spmv0_kernel(const int* __restrict__ row, const int* __restrict__ col,
                             const float* __restrict__ w, const float* __restrict__ dinv,
                             const float* __restrict__ x, float* __restrict__ y, int E) {
    int stride = gridDim.x * blockDim.x;
    for (int e = blockIdx.x * blockDim.x + threadIdx.x; e < E; e += stride) {
        int r = row[e], c = col[e];
        float nrm = dinv[r] * w[e] * dinv[c];
        atomicAdd(&y[c], nrm * x[r]);
    }
}

// out[i].k = relu(W[k]*y[i] + V[k]*x[i] + b[k])   (scalar y broadcast to K stacks)
__global__ void epi0_kernel(const float* __restrict__ y, const float* __restrict__ x,
                            const float* __restrict__ W, const float* __restrict__ V,
                            const float* __restrict__ b, float4* __restrict__ out, int n) {
    int i = blockIdx.x * blockDim.x + threadIdx.x;
    if (i >= n) return;
    float xi = x[i], yi = y[i];
    float4 o;
    o.x = fmaxf(fmaf(W[0], yi, fmaf(V[0], xi, b[0])), 0.f);
    o.y = fmaxf(fmaf(W[1], yi, fmaf(V[1], xi, b[1])), 0.f);
    o.z = fmaxf(fmaf(W[2], yi, fmaf(V[2], xi, b[2])), 0.f);
    o.w = 0.f;
    out[i] = o;
}

// ---------------- vector SpMV: y4[c][k] += norm_e * out[r][k], k<3 ----------------
__global__ void spmv_vec_kernel(const int* __restrict__ row, const int* __restrict__ col,
                                const float* __restrict__ w, const float* __restrict__ dinv,
                                const float4* __restrict__ out, float* __restrict__ y4, int E) {
    int stride = gridDim.x * blockDim.x;
    for (int e = blockIdx.x * blockDim.x + threadIdx.x; e < E; e += stride) {
        int r = row[e], c = col[e];
        float nrm = dinv[r] * w[e] * dinv[c];
        float4 v = out[r];
        atomicAdd(&y4[4 * c + 0], nrm * v.x);
        atomicAdd(&y4[4 * c + 1], nrm * v.y);
        atomicAdd(&y4[4 * c + 2], nrm * v.z);
    }
}

// out[i].k = relu(W[k]*y4[i][k] + V[k]*x[i] + b[k])
__global__ void epi_kernel(const float* __restrict__ y4, const float* __restrict__ x,
                           const float* __restrict__ W, const float* __restrict__ V,
                           const float* __restrict__ b, float4* __restrict__ out, int n) {
    int i = blockIdx.x * blockDim.x + threadIdx.x;
    if (i >= n) return;
    float xi = x[i];
    float4 o;
    o.x = fmaxf(fmaf(W[0], y4[4 * i + 0], fmaf(V[0], xi, b[0])), 0.f);
    o.y = fmaxf(fmaf(W[1], y4[4 * i + 1], fmaf(V[1], xi, b[1])), 0.f);
    o.z = fmaxf(fmaf(W[2], y4[4 * i + 2], fmaf(V[2], xi, b[2])), 0.f);
    o.w = 0.f;
    out[i] = o;
}

// ---------------- final: sigmoid(lin_w * mean_k(out) + lin_b) ----------------
__global__ void final_kernel(const float4* __restrict__ out, const float* __restrict__ lin_w,
                             const float* __restrict__ lin_b, float* __restrict__ o, int n) {
    int i = blockIdx.x * blockDim.x + threadIdx.x;
    if (i >= n) return;
    float4 v = out[i];
    float m = (v.x + v.y + v.z) * (1.f / 3.f);
    float z = fmaf(lin_w[0], m, lin_b[0]);
    o[i] = 1.f / (1.f + __expf(-z));
}

extern "C" void kernel_launch(void* const* d_in, const int* in_sizes, int n_in,
                              void* d_out, int out_size, void* d_ws, size_t ws_size,
                              hipStream_t stream) {
    const float* x      = (const float*)d_in[0];
    const int*   eidx   = (const int*)d_in[1];       // [2, E] as int32
    const float* w      = (const float*)d_in[2];     // [E]
    const float* initW  = (const float*)d_in[3];     // [K]
    const float* weight = (const float*)d_in[4];     // [T-1, K]
    const float* rootW  = (const float*)d_in[5];     // [T, K]
    const float* bias   = (const float*)d_in[6];     // [T, K]
    const float* lin_w  = (const float*)d_in[7];     // [1]
    const float* lin_b  = (const float*)d_in[8];     // [1]
    float* outp = (float*)d_out;

    const int* row = eidx;
    const int* col = eidx + EE;

    // workspace layout: dinv [N] | y [4N] | out [4N]
    float* dinv = (float*)d_ws;
    float* y    = dinv + NN;
    float4* st  = (float4*)(y + 4 * (size_t)NN);

    const int TPB = 256;
    const int gridN = (NN + TPB - 1) / TPB;
    const int gridE = 4096;  // grid-stride over edges

    // deg -> dinv
    hipMemsetAsync(dinv, 0, NN * sizeof(float), stream);
    deg_kernel<<<gridE, TPB, 0, stream>>>(col, w, dinv, EE);
    dinv_kernel<<<gridN, TPB, 0, stream>>>(dinv, NN);

    // layer 0: one scalar SpMV (A_hat @ x), shared across stacks
    hipMemsetAsync(y, 0, NN * sizeof(float), stream);
    spmv0_kernel<<<gridE, TPB, 0, stream>>>(row, col, w, dinv, x, y, EE);
    epi0_kernel<<<gridN, TPB, 0, stream>>>(y, x, initW, rootW + 0 * KK, bias + 0 * KK, st, NN);

    // layers 1..T-1: vector SpMV on the 3-stack state
    for (int t = 1; t < TT; ++t) {
        hipMemsetAsync(y, 0, 4 * (size_t)NN * sizeof(float), stream);
        spmv_vec_kernel<<<gridE, TPB, 0, stream>>>(row, col, w, dinv, st, y, EE);
        epi_kernel<<<gridN, TPB, 0, stream>>>(y, x, weight + (t - 1) * KK,
                                              rootW + t * KK, bias + t * KK, st, NN);
    }

    // mean over stacks -> linear -> sigmoid
    final_kernel<<<gridN, TPB, 0, stream>>>(st, lin_w, lin_b, outp, NN);
}

// Round 2
// 8452.216 us; speedup vs baseline: 2.0474x; 2.0474x over previous
//
#include <hip/hip_runtime.h>

// Problem constants (from reference); N/E taken from in_sizes at runtime.
constexpr int KK = 3;         // stacks
constexpr int TT = 4;         // layers
constexpr int SCAN_BLOCK = 1024;

__device__ __forceinline__ float relu_(float v) { return fmaxf(v, 0.f); }

// =================== CSR-pull path ===================

// Edge sweep: in-degree count (int) + weighted degree (float) per destination.
__global__ void count_deg_kernel(const int* __restrict__ col, const float* __restrict__ w,
                                 int* __restrict__ cnt, float* __restrict__ deg, int E) {
    int stride = gridDim.x * blockDim.x;
    for (int e = blockIdx.x * blockDim.x + threadIdx.x; e < E; e += stride) {
        int c = col[e];
        atomicAdd(&cnt[c], 1);
        atomicAdd(&deg[c], w[e]);
    }
}

__global__ void dinv_kernel(float* __restrict__ deg, int n) {
    int i = blockIdx.x * blockDim.x + threadIdx.x;
    if (i < n) {
        float d = deg[i];
        deg[i] = (d > 0.f) ? rsqrtf(d) : 0.f;
    }
}

// Block-local exclusive scan; emits per-block totals.
__global__ void scan1_kernel(const int* __restrict__ cnt, int* __restrict__ ptr,
                             int* __restrict__ partials, int n) {
    __shared__ int sm[SCAN_BLOCK];
    int i = blockIdx.x * SCAN_BLOCK + threadIdx.x;
    int v = (i < n) ? cnt[i] : 0;
    sm[threadIdx.x] = v;
    __syncthreads();
    for (int off = 1; off < SCAN_BLOCK; off <<= 1) {
        int t = (threadIdx.x >= (unsigned)off) ? sm[threadIdx.x - off] : 0;
        __syncthreads();
        sm[threadIdx.x] += t;
        __syncthreads();
    }
    if (i < n) ptr[i] = sm[threadIdx.x] - v;               // exclusive
    if (threadIdx.x == SCAN_BLOCK - 1) partials[blockIdx.x] = sm[threadIdx.x];
}

// Single-block exclusive scan of the partials (np <= 1024).
__global__ void scan2_kernel(int* __restrict__ partials, int np) {
    __shared__ int sm[SCAN_BLOCK];
    int v = (threadIdx.x < (unsigned)np) ? partials[threadIdx.x] : 0;
    sm[threadIdx.x] = v;
    __syncthreads();
    for (int off = 1; off < SCAN_BLOCK; off <<= 1) {
        int t = (threadIdx.x >= (unsigned)off) ? sm[threadIdx.x - off] : 0;
        __syncthreads();
        sm[threadIdx.x] += t;
        __syncthreads();
    }
    if (threadIdx.x < (unsigned)np) partials[threadIdx.x] = sm[threadIdx.x] - v;
}

// Add block offsets; materialize ptr and the scatter cursors.
__global__ void scan3_kernel(int* __restrict__ ptr, int* __restrict__ cur,
                             const int* __restrict__ partials, int n, int E) {
    int i = blockIdx.x * SCAN_BLOCK + threadIdx.x;
    if (i < n) {
        int v = ptr[i] + partials[blockIdx.x];
        ptr[i] = v;
        cur[i] = v;
    }
    if (i == 0) ptr[n] = E;
}

// Scatter edges into destination buckets: pairs[pos] = {src_bits, w*dinv[src]}
__global__ void scatter_kernel(const int* __restrict__ row, const int* __restrict__ col,
                               const float* __restrict__ w, const float* __restrict__ dinv,
                               int* __restrict__ cur, float2* __restrict__ pairs, int E) {
    int stride = gridDim.x * blockDim.x;
    for (int e = blockIdx.x * blockDim.x + threadIdx.x; e < E; e += stride) {
        int r = row[e], c = col[e];
        int pos = atomicAdd(&cur[c], 1);
        float2 p;
        p.x = __int_as_float(r);
        p.y = w[e] * dinv[r];
        pairs[pos] = p;
    }
}

// Layer-0 pull: s_i = dinv[i] * sum pw*x[src]; st_i.k = relu(W0k*s + V0k*x_i + b0k)
__global__ void pull0_kernel(const int* __restrict__ ptr, const float2* __restrict__ pairs,
                             const float* __restrict__ x, const float* __restrict__ dinv,
                             const float* __restrict__ W, const float* __restrict__ V,
                             const float* __restrict__ b, float4* __restrict__ st, int n) {
    int i = blockIdx.x * blockDim.x + threadIdx.x;
    if (i >= n) return;
    int beg = ptr[i], end = ptr[i + 1];
    float s = 0.f;
    for (int j = beg; j < end; ++j) {
        float2 p = pairs[j];
        s += p.y * x[__float_as_int(p.x)];
    }
    s *= dinv[i];
    float xi = x[i];
    float4 o;
    o.x = relu_(fmaf(W[0], s, fmaf(V[0], xi, b[0])));
    o.y = relu_(fmaf(W[1], s, fmaf(V[1], xi, b[1])));
    o.z = relu_(fmaf(W[2], s, fmaf(V[2], xi, b[2])));
    o.w = 0.f;
    st[i] = o;
}

// Mid-layer pull on the 3-stack state (ping-pong in/out).
__global__ void pullv_kernel(const int* __restrict__ ptr, const float2* __restrict__ pairs,
                             const float4* __restrict__ stIn, const float* __restrict__ x,
                             const float* __restrict__ dinv, const float* __restrict__ W,
                             const float* __restrict__ V, const float* __restrict__ b,
                             float4* __restrict__ stOut, int n) {
    int i = blockIdx.x * blockDim.x + threadIdx.x;
    if (i >= n) return;
    int beg = ptr[i], end = ptr[i + 1];
    float sx = 0.f, sy = 0.f, sz = 0.f;
    for (int j = beg; j < end; ++j) {
        float2 p = pairs[j];
        float4 v = stIn[__float_as_int(p.x)];
        sx = fmaf(p.y, v.x, sx);
        sy = fmaf(p.y, v.y, sy);
        sz = fmaf(p.y, v.z, sz);
    }
    float di = dinv[i], xi = x[i];
    float4 o;
    o.x = relu_(fmaf(W[0], sx * di, fmaf(V[0], xi, b[0])));
    o.y = relu_(fmaf(W[1], sy * di, fmaf(V[1], xi, b[1])));
    o.z = relu_(fmaf(W[2], sz * di, fmaf(V[2], xi, b[2])));
    o.w = 0.f;
    stOut[i] = o;
}

// Last-layer pull fused with mean/linear/sigmoid.
__global__ void pull_final_kernel(const int* __restrict__ ptr, const float2* __restrict__ pairs,
                                  const float4* __restrict__ stIn, const float* __restrict__ x,
                                  const float* __restrict__ dinv, const float* __restrict__ W,
                                  const float* __restrict__ V, const float* __restrict__ b,
                                  const float* __restrict__ lin_w, const float* __restrict__ lin_b,
                                  float* __restrict__ outp, int n) {
    int i = blockIdx.x * blockDim.x + threadIdx.x;
    if (i >= n) return;
    int beg = ptr[i], end = ptr[i + 1];
    float sx = 0.f, sy = 0.f, sz = 0.f;
    for (int j = beg; j < end; ++j) {
        float2 p = pairs[j];
        float4 v = stIn[__float_as_int(p.x)];
        sx = fmaf(p.y, v.x, sx);
        sy = fmaf(p.y, v.y, sy);
        sz = fmaf(p.y, v.z, sz);
    }
    float di = dinv[i], xi = x[i];
    float ox = relu_(fmaf(W[0], sx * di, fmaf(V[0], xi, b[0])));
    float oy = relu_(fmaf(W[1], sy * di, fmaf(V[1], xi, b[1])));
    float oz = relu_(fmaf(W[2], sz * di, fmaf(V[2], xi, b[2])));
    float m = (ox + oy + oz) * (1.f / 3.f);
    float z = fmaf(lin_w[0], m, lin_b[0]);
    outp[i] = 1.f / (1.f + __expf(-z));
}

// =================== fallback (round-1 push-atomic path) ===================

__global__ void fb_deg_kernel(const int* __restrict__ col, const float* __restrict__ w,
                              float* __restrict__ deg, int E) {
    int stride = gridDim.x * blockDim.x;
    for (int e = blockIdx.x * blockDim.x + threadIdx.x; e < E; e += stride)
        atomicAdd(&deg[col[e]], w[e]);
}

__global__ void fb_spmv0_kernel(const int* __restrict__ row, const int* __restrict__ col,
                                const float* __restrict__ w, const float* __restrict__ dinv,
                                const float* __restrict__ x, float* __restrict__ y, int E) {
    int stride = gridDim.x * blockDim.x;
    for (int e = blockIdx.x * blockDim.x + threadIdx.x; e < E; e += stride) {
        int r = row[e], c = col[e];
        float nrm = dinv[r] * w[e] * dinv[c];
        atomicAdd(&y[c], nrm * x[r]);
    }
}

__global__ void fb_epi0_kernel(const float* __restrict__ y, const float* __restrict__ x,
                               const float* __restrict__ W, const float* __restrict__ V,
                               const float* __restrict__ b, float4* __restrict__ out, int n) {
    int i = blockIdx.x * blockDim.x + threadIdx.x;
    if (i >= n) return;
    float xi = x[i], yi = y[i];
    float4 o;
    o.x = relu_(fmaf(W[0], yi, fmaf(V[0], xi, b[0])));
    o.y = relu_(fmaf(W[1], yi, fmaf(V[1], xi, b[1])));
    o.z = relu_(fmaf(W[2], yi, fmaf(V[2], xi, b[2])));
    o.w = 0.f;
    out[i] = o;
}

__global__ void fb_spmv_vec_kernel(const int* __restrict__ row, const int* __restrict__ col,
                                   const float* __restrict__ w, const float* __restrict__ dinv,
                                   const float4* __restrict__ out, float* __restrict__ y4, int E) {
    int stride = gridDim.x * blockDim.x;
    for (int e = blockIdx.x * blockDim.x + threadIdx.x; e < E; e += stride) {
        int r = row[e], c = col[e];
        float nrm = dinv[r] * w[e] * dinv[c];
        float4 v = out[r];
        atomicAdd(&y4[4 * c + 0], nrm * v.x);
        atomicAdd(&y4[4 * c + 1], nrm * v.y);
        atomicAdd(&y4[4 * c + 2], nrm * v.z);
    }
}

__global__ void fb_epi_kernel(const float* __restrict__ y4, const float* __restrict__ x,
                              const float* __restrict__ W, const float* __restrict__ V,
                              const float* __restrict__ b, float4* __restrict__ out, int n) {
    int i = blockIdx.x * blockDim.x + threadIdx.x;
    if (i >= n) return;
    float xi = x[i];
    float4 o;
    o.x = relu_(fmaf(W[0], y4[4 * i + 0], fmaf(V[0], xi, b[0])));
    o.y = relu_(fmaf(W[1], y4[4 * i + 1], fmaf(V[1], xi, b[1])));
    o.z = relu_(fmaf(W[2], y4[4 * i + 2], fmaf(V[2], xi, b[2])));
    o.w = 0.f;
    out[i] = o;
}

__global__ void fb_final_kernel(const float4* __restrict__ out, const float* __restrict__ lin_w,
                                const float* __restrict__ lin_b, float* __restrict__ o, int n) {
    int i = blockIdx.x * blockDim.x + threadIdx.x;
    if (i >= n) return;
    float4 v = out[i];
    float m = (v.x + v.y + v.z) * (1.f / 3.f);
    float z = fmaf(lin_w[0], m, lin_b[0]);
    o[i] = 1.f / (1.f + __expf(-z));
}

// =================== launch ===================

extern "C" void kernel_launch(void* const* d_in, const int* in_sizes, int n_in,
                              void* d_out, int out_size, void* d_ws, size_t ws_size,
                              hipStream_t stream) {
    const float* x      = (const float*)d_in[0];
    const int*   eidx   = (const int*)d_in[1];       // [2, E] int32
    const float* w      = (const float*)d_in[2];     // [E]
    const float* initW  = (const float*)d_in[3];     // [K]
    const float* weight = (const float*)d_in[4];     // [T-1, K]
    const float* rootW  = (const float*)d_in[5];     // [T, K]
    const float* bias   = (const float*)d_in[6];     // [T, K]
    const float* lin_w  = (const float*)d_in[7];     // [1]
    const float* lin_b  = (const float*)d_in[8];     // [1]
    float* outp = (float*)d_out;

    const int N = in_sizes[0];
    const int E = in_sizes[2];
    const int* row = eidx;
    const int* col = eidx + (size_t)E;

    const int TPB = 256;
    const int gridN  = (N + TPB - 1) / TPB;
    const int gridE  = 8192;
    const int nScanB = (N + SCAN_BLOCK - 1) / SCAN_BLOCK;   // <= 1024 for N <= 1M

    // ---- workspace layout (16B-aligned chunks) ----
    auto align16 = [](size_t v) { return (v + 15) & ~(size_t)15; };
    size_t off = 0;
    size_t pairsOff    = off; off += align16((size_t)E * 8);          // float2[E]
    size_t stAOff      = off; off += align16((size_t)N * 16);         // float4[N]
    size_t stBOff      = off; off += align16((size_t)N * 16);         // float4[N]
    size_t dinvOff     = off; off += align16((size_t)N * 4);
    size_t cntOff      = off; off += align16((size_t)N * 4);
    size_t ptrOff      = off; off += align16((size_t)(N + 1) * 4);
    size_t curOff      = off; off += align16((size_t)N * 4);
    size_t partialsOff = off; off += align16((size_t)SCAN_BLOCK * 4);
    size_t needed = off;

    char* wsb = (char*)d_ws;

    if (ws_size >= needed && nScanB <= SCAN_BLOCK) {
        float2* pairs  = (float2*)(wsb + pairsOff);
        float4* stA    = (float4*)(wsb + stAOff);
        float4* stB    = (float4*)(wsb + stBOff);
        float* dinv    = (float*)(wsb + dinvOff);
        int* cnt       = (int*)(wsb + cntOff);
        int* ptr       = (int*)(wsb + ptrOff);
        int* cur       = (int*)(wsb + curOff);
        int* partials  = (int*)(wsb + partialsOff);

        hipMemsetAsync(cnt, 0, (size_t)N * 4, stream);
        hipMemsetAsync(dinv, 0, (size_t)N * 4, stream);

        // build: count + weighted degree, dinv, scan, scatter
        count_deg_kernel<<<gridE, TPB, 0, stream>>>(col, w, cnt, dinv, E);
        dinv_kernel<<<gridN, TPB, 0, stream>>>(dinv, N);
        scan1_kernel<<<nScanB, SCAN_BLOCK, 0, stream>>>(cnt, ptr, partials, N);
        scan2_kernel<<<1, SCAN_BLOCK, 0, stream>>>(partials, nScanB);
        scan3_kernel<<<nScanB, SCAN_BLOCK, 0, stream>>>(ptr, cur, partials, N, E);
        scatter_kernel<<<gridE, TPB, 0, stream>>>(row, col, w, dinv, cur, pairs, E);

        // layer 0 (scalar pull) -> stA
        pull0_kernel<<<gridN, TPB, 0, stream>>>(ptr, pairs, x, dinv, initW,
                                                rootW + 0 * KK, bias + 0 * KK, stA, N);
        // layers 1,2 (vector pulls, ping-pong)
        pullv_kernel<<<gridN, TPB, 0, stream>>>(ptr, pairs, stA, x, dinv, weight + 0 * KK,
                                                rootW + 1 * KK, bias + 1 * KK, stB, N);
        pullv_kernel<<<gridN, TPB, 0, stream>>>(ptr, pairs, stB, x, dinv, weight + 1 * KK,
                                                rootW + 2 * KK, bias + 2 * KK, stA, N);
        // layer 3 fused with mean/linear/sigmoid
        pull_final_kernel<<<gridN, TPB, 0, stream>>>(ptr, pairs, stA, x, dinv, weight + 2 * KK,
                                                     rootW + 3 * KK, bias + 3 * KK,
                                                     lin_w, lin_b, outp, N);
        return;
    }

    // ---------- fallback: round-1 push-atomic path ----------
    float* dinv = (float*)d_ws;
    float* y    = dinv + N;
    float4* st  = (float4*)(y + 4 * (size_t)N);

    hipMemsetAsync(dinv, 0, (size_t)N * 4, stream);
    fb_deg_kernel<<<4096, TPB, 0, stream>>>(col, w, dinv, E);
    dinv_kernel<<<gridN, TPB, 0, stream>>>(dinv, N);

    hipMemsetAsync(y, 0, (size_t)N * 4, stream);
    fb_spmv0_kernel<<<4096, TPB, 0, stream>>>(row, col, w, dinv, x, y, E);
    fb_epi0_kernel<<<gridN, TPB, 0, stream>>>(y, x, initW, rootW + 0 * KK, bias + 0 * KK, st, N);

    for (int t = 1; t < TT; ++t) {
        hipMemsetAsync(y, 0, 4 * (size_t)N * sizeof(float), stream);
        fb_spmv_vec_kernel<<<4096, TPB, 0, stream>>>(row, col, w, dinv, st, y, E);
        fb_epi_kernel<<<gridN, TPB, 0, stream>>>(y, x, weight + (t - 1) * KK,
                                                 rootW + t * KK, bias + t * KK, st, N);
    }
    fb_final_kernel<<<gridN, TPB, 0, stream>>>(st, lin_w, lin_b, outp, N);
}

// Round 3
// 6999.744 us; speedup vs baseline: 2.4723x; 1.2075x over previous
//
#include <hip/hip_runtime.h>

// Problem constants (from reference); N/E taken from in_sizes at runtime.
constexpr int KK = 3;         // stacks
constexpr int SCAN_BLOCK = 1024;

__device__ __forceinline__ float relu_(float v) { return fmaxf(v, 0.f); }

// =================== shared helpers (both paths) ===================

__global__ void dinv_kernel(float* __restrict__ deg, int n) {
    int i = blockIdx.x * blockDim.x + threadIdx.x;
    if (i < n) {
        float d = deg[i];
        deg[i] = (d > 0.f) ? rsqrtf(d) : 0.f;
    }
}

// Block-local exclusive scan; emits per-block totals.
__global__ void scan1_kernel(const int* __restrict__ cnt, int* __restrict__ ptr,
                             int* __restrict__ partials, int n) {
    __shared__ int sm[SCAN_BLOCK];
    int i = blockIdx.x * SCAN_BLOCK + threadIdx.x;
    int v = (i < n) ? cnt[i] : 0;
    sm[threadIdx.x] = v;
    __syncthreads();
    for (int off = 1; off < SCAN_BLOCK; off <<= 1) {
        int t = (threadIdx.x >= (unsigned)off) ? sm[threadIdx.x - off] : 0;
        __syncthreads();
        sm[threadIdx.x] += t;
        __syncthreads();
    }
    if (i < n) ptr[i] = sm[threadIdx.x] - v;               // exclusive
    if (threadIdx.x == SCAN_BLOCK - 1) partials[blockIdx.x] = sm[threadIdx.x];
}

// Single-block exclusive scan of the partials (np <= 1024).
__global__ void scan2_kernel(int* __restrict__ partials, int np) {
    __shared__ int sm[SCAN_BLOCK];
    int v = (threadIdx.x < (unsigned)np) ? partials[threadIdx.x] : 0;
    sm[threadIdx.x] = v;
    __syncthreads();
    for (int off = 1; off < SCAN_BLOCK; off <<= 1) {
        int t = (threadIdx.x >= (unsigned)off) ? sm[threadIdx.x - off] : 0;
        __syncthreads();
        sm[threadIdx.x] += t;
        __syncthreads();
    }
    if (threadIdx.x < (unsigned)np) partials[threadIdx.x] = sm[threadIdx.x] - v;
}

// Add block offsets; materialize ptr (+ optional cursors for fallback path).
__global__ void scan3_kernel(int* __restrict__ ptr, int* __restrict__ cur,
                             const int* __restrict__ partials, int n, int E) {
    int i = blockIdx.x * SCAN_BLOCK + threadIdx.x;
    if (i < n) {
        int v = ptr[i] + partials[blockIdx.x];
        ptr[i] = v;
        if (cur) cur[i] = v;
    }
    if (i == 0) ptr[n] = E;
}

// =================== new build: 1 atomic / edge ===================

// pos[e] = atomicAdd(&cnt[col[e]], 1)  — count AND slot reservation in one.
__global__ void count_pos_kernel(const int* __restrict__ col, int* __restrict__ cnt,
                                 int* __restrict__ pos, int E) {
    int stride = gridDim.x * blockDim.x;
    for (int e = blockIdx.x * blockDim.x + threadIdx.x; e < E; e += stride)
        pos[e] = atomicAdd(&cnt[col[e]], 1);
}

// Atomic-free scatter: pairs[ptr[col[e]] + pos[e]] = {src_bits, raw w}
__global__ void scatter2_kernel(const int* __restrict__ row, const int* __restrict__ col,
                                const float* __restrict__ w, const int* __restrict__ ptr,
                                const int* __restrict__ pos, float2* __restrict__ pairs, int E) {
    int stride = gridDim.x * blockDim.x;
    for (int e = blockIdx.x * blockDim.x + threadIdx.x; e < E; e += stride) {
        float2 p;
        p.x = __int_as_float(row[e]);
        p.y = w[e];
        pairs[ptr[col[e]] + pos[e]] = p;
    }
}

// deg[i] = sum of raw w over bucket i; store dinv in place.
__global__ void degsum_kernel(const int* __restrict__ ptr, const float2* __restrict__ pairs,
                              float* __restrict__ dinv, int n) {
    int i = blockIdx.x * blockDim.x + threadIdx.x;
    if (i >= n) return;
    int beg = ptr[i], end = ptr[i + 1];
    float s = 0.f;
    for (int j = beg; j < end; ++j) s += pairs[j].y;
    dinv[i] = (s > 0.f) ? rsqrtf(s) : 0.f;
}

// pairs[e].y *= dinv[src]
__global__ void fixup_kernel(float2* __restrict__ pairs, const float* __restrict__ dinv, int E) {
    int stride = gridDim.x * blockDim.x;
    for (int e = blockIdx.x * blockDim.x + threadIdx.x; e < E; e += stride) {
        float2 p = pairs[e];
        p.y *= dinv[__float_as_int(p.x)];
        pairs[e] = p;
    }
}

// =================== pull kernels (unchanged) ===================

__global__ void pull0_kernel(const int* __restrict__ ptr, const float2* __restrict__ pairs,
                             const float* __restrict__ x, const float* __restrict__ dinv,
                             const float* __restrict__ W, const float* __restrict__ V,
                             const float* __restrict__ b, float4* __restrict__ st, int n) {
    int i = blockIdx.x * blockDim.x + threadIdx.x;
    if (i >= n) return;
    int beg = ptr[i], end = ptr[i + 1];
    float s = 0.f;
    for (int j = beg; j < end; ++j) {
        float2 p = pairs[j];
        s += p.y * x[__float_as_int(p.x)];
    }
    s *= dinv[i];
    float xi = x[i];
    float4 o;
    o.x = relu_(fmaf(W[0], s, fmaf(V[0], xi, b[0])));
    o.y = relu_(fmaf(W[1], s, fmaf(V[1], xi, b[1])));
    o.z = relu_(fmaf(W[2], s, fmaf(V[2], xi, b[2])));
    o.w = 0.f;
    st[i] = o;
}

__global__ void pullv_kernel(const int* __restrict__ ptr, const float2* __restrict__ pairs,
                             const float4* __restrict__ stIn, const float* __restrict__ x,
                             const float* __restrict__ dinv, const float* __restrict__ W,
                             const float* __restrict__ V, const float* __restrict__ b,
                             float4* __restrict__ stOut, int n) {
    int i = blockIdx.x * blockDim.x + threadIdx.x;
    if (i >= n) return;
    int beg = ptr[i], end = ptr[i + 1];
    float sx = 0.f, sy = 0.f, sz = 0.f;
    for (int j = beg; j < end; ++j) {
        float2 p = pairs[j];
        float4 v = stIn[__float_as_int(p.x)];
        sx = fmaf(p.y, v.x, sx);
        sy = fmaf(p.y, v.y, sy);
        sz = fmaf(p.y, v.z, sz);
    }
    float di = dinv[i], xi = x[i];
    float4 o;
    o.x = relu_(fmaf(W[0], sx * di, fmaf(V[0], xi, b[0])));
    o.y = relu_(fmaf(W[1], sy * di, fmaf(V[1], xi, b[1])));
    o.z = relu_(fmaf(W[2], sz * di, fmaf(V[2], xi, b[2])));
    o.w = 0.f;
    stOut[i] = o;
}

__global__ void pull_final_kernel(const int* __restrict__ ptr, const float2* __restrict__ pairs,
                                  const float4* __restrict__ stIn, const float* __restrict__ x,
                                  const float* __restrict__ dinv, const float* __restrict__ W,
                                  const float* __restrict__ V, const float* __restrict__ b,
                                  const float* __restrict__ lin_w, const float* __restrict__ lin_b,
                                  float* __restrict__ outp, int n) {
    int i = blockIdx.x * blockDim.x + threadIdx.x;
    if (i >= n) return;
    int beg = ptr[i], end = ptr[i + 1];
    float sx = 0.f, sy = 0.f, sz = 0.f;
    for (int j = beg; j < end; ++j) {
        float2 p = pairs[j];
        float4 v = stIn[__float_as_int(p.x)];
        sx = fmaf(p.y, v.x, sx);
        sy = fmaf(p.y, v.y, sy);
        sz = fmaf(p.y, v.z, sz);
    }
    float di = dinv[i], xi = x[i];
    float ox = relu_(fmaf(W[0], sx * di, fmaf(V[0], xi, b[0])));
    float oy = relu_(fmaf(W[1], sy * di, fmaf(V[1], xi, b[1])));
    float oz = relu_(fmaf(W[2], sz * di, fmaf(V[2], xi, b[2])));
    float m = (ox + oy + oz) * (1.f / 3.f);
    float z = fmaf(lin_w[0], m, lin_b[0]);
    outp[i] = 1.f / (1.f + __expf(-z));
}

// =================== fallback build (round-2: 3 atomics/edge) ===================

__global__ void count_deg_kernel(const int* __restrict__ col, const float* __restrict__ w,
                                 int* __restrict__ cnt, float* __restrict__ deg, int E) {
    int stride = gridDim.x * blockDim.x;
    for (int e = blockIdx.x * blockDim.x + threadIdx.x; e < E; e += stride) {
        int c = col[e];
        atomicAdd(&cnt[c], 1);
        atomicAdd(&deg[c], w[e]);
    }
}

__global__ void scatter_kernel(const int* __restrict__ row, const int* __restrict__ col,
                               const float* __restrict__ w, const float* __restrict__ dinv,
                               int* __restrict__ cur, float2* __restrict__ pairs, int E) {
    int stride = gridDim.x * blockDim.x;
    for (int e = blockIdx.x * blockDim.x + threadIdx.x; e < E; e += stride) {
        int r = row[e], c = col[e];
        int posv = atomicAdd(&cur[c], 1);
        float2 p;
        p.x = __int_as_float(r);
        p.y = w[e] * dinv[r];
        pairs[posv] = p;
    }
}

// =================== launch ===================

extern "C" void kernel_launch(void* const* d_in, const int* in_sizes, int n_in,
                              void* d_out, int out_size, void* d_ws, size_t ws_size,
                              hipStream_t stream) {
    const float* x      = (const float*)d_in[0];
    const int*   eidx   = (const int*)d_in[1];       // [2, E] int32
    const float* w      = (const float*)d_in[2];     // [E]
    const float* initW  = (const float*)d_in[3];     // [K]
    const float* weight = (const float*)d_in[4];     // [T-1, K]
    const float* rootW  = (const float*)d_in[5];     // [T, K]
    const float* bias   = (const float*)d_in[6];     // [T, K]
    const float* lin_w  = (const float*)d_in[7];     // [1]
    const float* lin_b  = (const float*)d_in[8];     // [1]
    float* outp = (float*)d_out;

    const int N = in_sizes[0];
    const int E = in_sizes[2];
    const int* row = eidx;
    const int* col = eidx + (size_t)E;

    const int TPB = 256;
    const int gridN  = (N + TPB - 1) / TPB;
    const int gridE  = 8192;
    const int nScanB = (N + SCAN_BLOCK - 1) / SCAN_BLOCK;   // <= 1024 for N <= 1M

    auto align16 = [](size_t v) { return (v + 15) & ~(size_t)15; };

    // ---- primary layout: pairs | pos | stA | stB | dinv | cnt | ptr | partials ----
    {
        size_t off = 0;
        size_t pairsOff    = off; off += align16((size_t)E * 8);
        size_t posOff      = off; off += align16((size_t)E * 4);
        size_t stAOff      = off; off += align16((size_t)N * 16);
        size_t stBOff      = off; off += align16((size_t)N * 16);
        size_t dinvOff     = off; off += align16((size_t)N * 4);
        size_t cntOff      = off; off += align16((size_t)N * 4);
        size_t ptrOff      = off; off += align16((size_t)(N + 1) * 4);
        size_t partialsOff = off; off += align16((size_t)SCAN_BLOCK * 4);
        size_t needed = off;

        if (ws_size >= needed && nScanB <= SCAN_BLOCK) {
            char* wsb = (char*)d_ws;
            float2* pairs = (float2*)(wsb + pairsOff);
            int*    pos   = (int*)(wsb + posOff);
            float4* stA   = (float4*)(wsb + stAOff);
            float4* stB   = (float4*)(wsb + stBOff);
            float*  dinv  = (float*)(wsb + dinvOff);
            int*    cnt   = (int*)(wsb + cntOff);
            int*    ptr   = (int*)(wsb + ptrOff);
            int*    parts = (int*)(wsb + partialsOff);

            hipMemsetAsync(cnt, 0, (size_t)N * 4, stream);

            // build: 1 atomic per edge
            count_pos_kernel<<<gridE, TPB, 0, stream>>>(col, cnt, pos, E);
            scan1_kernel<<<nScanB, SCAN_BLOCK, 0, stream>>>(cnt, ptr, parts, N);
            scan2_kernel<<<1, SCAN_BLOCK, 0, stream>>>(parts, nScanB);
            scan3_kernel<<<nScanB, SCAN_BLOCK, 0, stream>>>(ptr, nullptr, parts, N, E);
            scatter2_kernel<<<gridE, TPB, 0, stream>>>(row, col, w, ptr, pos, pairs, E);
            degsum_kernel<<<gridN, TPB, 0, stream>>>(ptr, pairs, dinv, N);
            fixup_kernel<<<gridE, TPB, 0, stream>>>(pairs, dinv, E);

            // layers
            pull0_kernel<<<gridN, TPB, 0, stream>>>(ptr, pairs, x, dinv, initW,
                                                    rootW + 0 * KK, bias + 0 * KK, stA, N);
            pullv_kernel<<<gridN, TPB, 0, stream>>>(ptr, pairs, stA, x, dinv, weight + 0 * KK,
                                                    rootW + 1 * KK, bias + 1 * KK, stB, N);
            pullv_kernel<<<gridN, TPB, 0, stream>>>(ptr, pairs, stB, x, dinv, weight + 1 * KK,
                                                    rootW + 2 * KK, bias + 2 * KK, stA, N);
            pull_final_kernel<<<gridN, TPB, 0, stream>>>(ptr, pairs, stA, x, dinv, weight + 2 * KK,
                                                         rootW + 3 * KK, bias + 3 * KK,
                                                         lin_w, lin_b, outp, N);
            return;
        }
    }

    // ---- fallback: round-2 CSR path (3 atomics/edge build) ----
    {
        size_t off = 0;
        size_t pairsOff    = off; off += align16((size_t)E * 8);
        size_t stAOff      = off; off += align16((size_t)N * 16);
        size_t stBOff      = off; off += align16((size_t)N * 16);
        size_t dinvOff     = off; off += align16((size_t)N * 4);
        size_t cntOff      = off; off += align16((size_t)N * 4);
        size_t ptrOff      = off; off += align16((size_t)(N + 1) * 4);
        size_t curOff      = off; off += align16((size_t)N * 4);
        size_t partialsOff = off; off += align16((size_t)SCAN_BLOCK * 4);

        char* wsb = (char*)d_ws;
        float2* pairs = (float2*)(wsb + pairsOff);
        float4* stA   = (float4*)(wsb + stAOff);
        float4* stB   = (float4*)(wsb + stBOff);
        float*  dinv  = (float*)(wsb + dinvOff);
        int*    cnt   = (int*)(wsb + cntOff);
        int*    ptr   = (int*)(wsb + ptrOff);
        int*    cur   = (int*)(wsb + curOff);
        int*    parts = (int*)(wsb + partialsOff);

        hipMemsetAsync(cnt, 0, (size_t)N * 4, stream);
        hipMemsetAsync(dinv, 0, (size_t)N * 4, stream);

        count_deg_kernel<<<gridE, TPB, 0, stream>>>(col, w, cnt, dinv, E);
        dinv_kernel<<<gridN, TPB, 0, stream>>>(dinv, N);
        scan1_kernel<<<nScanB, SCAN_BLOCK, 0, stream>>>(cnt, ptr, parts, N);
        scan2_kernel<<<1, SCAN_BLOCK, 0, stream>>>(parts, nScanB);
        scan3_kernel<<<nScanB, SCAN_BLOCK, 0, stream>>>(ptr, cur, parts, N, E);
        scatter_kernel<<<gridE, TPB, 0, stream>>>(row, col, w, dinv, cur, pairs, E);

        pull0_kernel<<<gridN, TPB, 0, stream>>>(ptr, pairs, x, dinv, initW,
                                                rootW + 0 * KK, bias + 0 * KK, stA, N);
        pullv_kernel<<<gridN, TPB, 0, stream>>>(ptr, pairs, stA, x, dinv, weight + 0 * KK,
                                                rootW + 1 * KK, bias + 1 * KK, stB, N);
        pullv_kernel<<<gridN, TPB, 0, stream>>>(ptr, pairs, stB, x, dinv, weight + 1 * KK,
                                                rootW + 2 * KK, bias + 2 * KK, stA, N);
        pull_final_kernel<<<gridN, TPB, 0, stream>>>(ptr, pairs, stA, x, dinv, weight + 2 * KK,
                                                     rootW + 3 * KK, bias + 3 * KK,
                                                     lin_w, lin_b, outp, N);
    }
}

// Round 4
// 5647.394 us; speedup vs baseline: 3.0643x; 1.2395x over previous
//
#include <hip/hip_runtime.h>

constexpr int KK = 3;         // stacks
constexpr int SCAN_BLOCK = 1024;
constexpr int RBITS = 10;                 // nodes per coarse bucket = 1024
constexpr int BUCK_NODES = 1 << RBITS;

__device__ __forceinline__ float relu_(float v) { return fmaxf(v, 0.f); }

// =================== radix build (primary) ===================

// Per-block LDS histogram of coarse buckets, then aggregated global adds.
__global__ void coarse_count_kernel(const int* __restrict__ col, int* __restrict__ coarseCnt,
                                    int E, int nbuck) {
    __shared__ int h[BUCK_NODES];
    for (int i = threadIdx.x; i < nbuck; i += blockDim.x) h[i] = 0;
    __syncthreads();
    long e0 = (long)blockIdx.x * E / gridDim.x;
    long e1 = (long)(blockIdx.x + 1) * E / gridDim.x;
    for (long e = e0 + threadIdx.x; e < e1; e += blockDim.x)
        atomicAdd(&h[col[e] >> RBITS], 1);
    __syncthreads();
    for (int i = threadIdx.x; i < nbuck; i += blockDim.x)
        if (h[i]) atomicAdd(&coarseCnt[i], h[i]);
}

// Single-block exclusive scan of coarseCnt -> coarseBase; init coarseCur.
__global__ void coarse_scan_kernel(const int* __restrict__ coarseCnt, int* __restrict__ coarseBase,
                                   int* __restrict__ coarseCur, int nbuck, int E) {
    __shared__ int sm[SCAN_BLOCK];
    int tid = threadIdx.x;
    int v = (tid < nbuck) ? coarseCnt[tid] : 0;
    sm[tid] = v;
    __syncthreads();
    for (int off = 1; off < SCAN_BLOCK; off <<= 1) {
        int t = (tid >= off) ? sm[tid - off] : 0;
        __syncthreads();
        sm[tid] += t;
        __syncthreads();
    }
    if (tid < nbuck) {
        int base = sm[tid] - v;
        coarseBase[tid] = base;
        coarseCur[tid] = base;
    }
    if (tid == 0) coarseBase[nbuck] = E;
}

// Partition edges into coarse buckets. One global atomic per (block,bucket).
// tmp[pos] = { (col_low<<20) | row , w_bits }
__global__ void partition_kernel(const int* __restrict__ row, const int* __restrict__ col,
                                 const float* __restrict__ w, int* __restrict__ coarseCur,
                                 uint2* __restrict__ tmp, int E, int nbuck) {
    __shared__ int h[BUCK_NODES];
    __shared__ int base[BUCK_NODES];
    for (int i = threadIdx.x; i < nbuck; i += blockDim.x) h[i] = 0;
    __syncthreads();
    long e0 = (long)blockIdx.x * E / gridDim.x;
    long e1 = (long)(blockIdx.x + 1) * E / gridDim.x;
    for (long e = e0 + threadIdx.x; e < e1; e += blockDim.x)
        atomicAdd(&h[col[e] >> RBITS], 1);
    __syncthreads();
    for (int i = threadIdx.x; i < nbuck; i += blockDim.x)
        base[i] = h[i] ? atomicAdd(&coarseCur[i], h[i]) : 0;
    __syncthreads();
    for (long e = e0 + threadIdx.x; e < e1; e += blockDim.x) {
        int c = col[e];
        int b = c >> RBITS;
        int pos = atomicAdd(&base[b], 1);
        uint2 t;
        t.x = ((unsigned)(c & (BUCK_NODES - 1)) << 20) | (unsigned)row[e];
        t.y = __float_as_uint(w[e]);
        tmp[pos] = t;
    }
}

// Per bucket: count + weighted-degree histograms -> ptr[], dinv[] (sequential writes).
__global__ void bucket_stats_kernel(const uint2* __restrict__ tmp, const int* __restrict__ coarseBase,
                                    float* __restrict__ dinv, int* __restrict__ ptr,
                                    int N, int E, int nbuck) {
    __shared__ int cnt[BUCK_NODES];
    __shared__ float ws[BUCK_NODES];
    int b = blockIdx.x, tid = threadIdx.x;
    cnt[tid] = 0;
    ws[tid] = 0.f;
    __syncthreads();
    int beg = coarseBase[b], end = coarseBase[b + 1];
    for (int j = beg + tid; j < end; j += blockDim.x) {
        uint2 t = tmp[j];
        int cl = t.x >> 20;
        atomicAdd(&cnt[cl], 1);
        atomicAdd(&ws[cl], __uint_as_float(t.y));
    }
    __syncthreads();
    int v = cnt[tid];
    // inclusive scan in place (Hillis-Steele)
    for (int off = 1; off < BUCK_NODES; off <<= 1) {
        int t = (tid >= off) ? cnt[tid - off] : 0;
        __syncthreads();
        cnt[tid] += t;
        __syncthreads();
    }
    int node = (b << RBITS) + tid;
    if (node < N) {
        ptr[node] = beg + (cnt[tid] - v);
        float s = ws[tid];
        dinv[node] = (s > 0.f) ? rsqrtf(s) : 0.f;
    }
    if (b == 0 && tid == 0) ptr[N] = E;
}

// Per bucket: scatter to final CSR pairs with w*dinv[src] folded in.
__global__ void bucket_scatter_kernel(const uint2* __restrict__ tmp, const int* __restrict__ coarseBase,
                                      const int* __restrict__ ptr, const float* __restrict__ dinv,
                                      float2* __restrict__ pairs, int N, int E, int nbuck) {
    __shared__ int cur[BUCK_NODES];
    int b = blockIdx.x, tid = threadIdx.x;
    int node = (b << RBITS) + tid;
    cur[tid] = (node < N) ? ptr[node] : 0;
    __syncthreads();
    int beg = coarseBase[b], end = coarseBase[b + 1];
    for (int j = beg + tid; j < end; j += blockDim.x) {
        uint2 t = tmp[j];
        int cl = t.x >> 20;
        int r = t.x & 0xFFFFF;
        int pos = atomicAdd(&cur[cl], 1);
        float2 p;
        p.x = __int_as_float(r);
        p.y = __uint_as_float(t.y) * dinv[r];
        pairs[pos] = p;
    }
}

// =================== pull kernels ===================

__global__ void pull0_kernel(const int* __restrict__ ptr, const float2* __restrict__ pairs,
                             const float* __restrict__ x, const float* __restrict__ dinv,
                             const float* __restrict__ W, const float* __restrict__ V,
                             const float* __restrict__ b, float4* __restrict__ st, int n) {
    int i = blockIdx.x * blockDim.x + threadIdx.x;
    if (i >= n) return;
    int beg = ptr[i], end = ptr[i + 1];
    float s = 0.f;
    for (int j = beg; j < end; ++j) {
        float2 p = pairs[j];
        s += p.y * x[__float_as_int(p.x)];
    }
    s *= dinv[i];
    float xi = x[i];
    float4 o;
    o.x = relu_(fmaf(W[0], s, fmaf(V[0], xi, b[0])));
    o.y = relu_(fmaf(W[1], s, fmaf(V[1], xi, b[1])));
    o.z = relu_(fmaf(W[2], s, fmaf(V[2], xi, b[2])));
    o.w = 0.f;
    st[i] = o;
}

__global__ void pullv_kernel(const int* __restrict__ ptr, const float2* __restrict__ pairs,
                             const float4* __restrict__ stIn, const float* __restrict__ x,
                             const float* __restrict__ dinv, const float* __restrict__ W,
                             const float* __restrict__ V, const float* __restrict__ b,
                             float4* __restrict__ stOut, int n) {
    int i = blockIdx.x * blockDim.x + threadIdx.x;
    if (i >= n) return;
    int beg = ptr[i], end = ptr[i + 1];
    float sx = 0.f, sy = 0.f, sz = 0.f;
    for (int j = beg; j < end; ++j) {
        float2 p = pairs[j];
        float4 v = stIn[__float_as_int(p.x)];
        sx = fmaf(p.y, v.x, sx);
        sy = fmaf(p.y, v.y, sy);
        sz = fmaf(p.y, v.z, sz);
    }
    float di = dinv[i], xi = x[i];
    float4 o;
    o.x = relu_(fmaf(W[0], sx * di, fmaf(V[0], xi, b[0])));
    o.y = relu_(fmaf(W[1], sy * di, fmaf(V[1], xi, b[1])));
    o.z = relu_(fmaf(W[2], sz * di, fmaf(V[2], xi, b[2])));
    o.w = 0.f;
    stOut[i] = o;
}

__global__ void pull_final_kernel(const int* __restrict__ ptr, const float2* __restrict__ pairs,
                                  const float4* __restrict__ stIn, const float* __restrict__ x,
                                  const float* __restrict__ dinv, const float* __restrict__ W,
                                  const float* __restrict__ V, const float* __restrict__ b,
                                  const float* __restrict__ lin_w, const float* __restrict__ lin_b,
                                  float* __restrict__ outp, int n) {
    int i = blockIdx.x * blockDim.x + threadIdx.x;
    if (i >= n) return;
    int beg = ptr[i], end = ptr[i + 1];
    float sx = 0.f, sy = 0.f, sz = 0.f;
    for (int j = beg; j < end; ++j) {
        float2 p = pairs[j];
        float4 v = stIn[__float_as_int(p.x)];
        sx = fmaf(p.y, v.x, sx);
        sy = fmaf(p.y, v.y, sy);
        sz = fmaf(p.y, v.z, sz);
    }
    float di = dinv[i], xi = x[i];
    float ox = relu_(fmaf(W[0], sx * di, fmaf(V[0], xi, b[0])));
    float oy = relu_(fmaf(W[1], sy * di, fmaf(V[1], xi, b[1])));
    float oz = relu_(fmaf(W[2], sz * di, fmaf(V[2], xi, b[2])));
    float m = (ox + oy + oz) * (1.f / 3.f);
    float z = fmaf(lin_w[0], m, lin_b[0]);
    outp[i] = 1.f / (1.f + __expf(-z));
}

// =================== fallback build (round-3: 1 atomic/edge) ===================

__global__ void count_pos_kernel(const int* __restrict__ col, int* __restrict__ cnt,
                                 int* __restrict__ pos, int E) {
    int stride = gridDim.x * blockDim.x;
    for (int e = blockIdx.x * blockDim.x + threadIdx.x; e < E; e += stride)
        pos[e] = atomicAdd(&cnt[col[e]], 1);
}

__global__ void scan1_kernel(const int* __restrict__ cnt, int* __restrict__ ptr,
                             int* __restrict__ partials, int n) {
    __shared__ int sm[SCAN_BLOCK];
    int i = blockIdx.x * SCAN_BLOCK + threadIdx.x;
    int v = (i < n) ? cnt[i] : 0;
    sm[threadIdx.x] = v;
    __syncthreads();
    for (int off = 1; off < SCAN_BLOCK; off <<= 1) {
        int t = (threadIdx.x >= (unsigned)off) ? sm[threadIdx.x - off] : 0;
        __syncthreads();
        sm[threadIdx.x] += t;
        __syncthreads();
    }
    if (i < n) ptr[i] = sm[threadIdx.x] - v;
    if (threadIdx.x == SCAN_BLOCK - 1) partials[blockIdx.x] = sm[threadIdx.x];
}

__global__ void scan2_kernel(int* __restrict__ partials, int np) {
    __shared__ int sm[SCAN_BLOCK];
    int v = (threadIdx.x < (unsigned)np) ? partials[threadIdx.x] : 0;
    sm[threadIdx.x] = v;
    __syncthreads();
    for (int off = 1; off < SCAN_BLOCK; off <<= 1) {
        int t = (threadIdx.x >= (unsigned)off) ? sm[threadIdx.x - off] : 0;
        __syncthreads();
        sm[threadIdx.x] += t;
        __syncthreads();
    }
    if (threadIdx.x < (unsigned)np) partials[threadIdx.x] = sm[threadIdx.x] - v;
}

__global__ void scan3_kernel(int* __restrict__ ptr, int* __restrict__ cur,
                             const int* __restrict__ partials, int n, int E) {
    int i = blockIdx.x * SCAN_BLOCK + threadIdx.x;
    if (i < n) {
        int v = ptr[i] + partials[blockIdx.x];
        ptr[i] = v;
        if (cur) cur[i] = v;
    }
    if (i == 0) ptr[n] = E;
}

__global__ void scatter2_kernel(const int* __restrict__ row, const int* __restrict__ col,
                                const float* __restrict__ w, const int* __restrict__ ptr,
                                const int* __restrict__ pos, float2* __restrict__ pairs, int E) {
    int stride = gridDim.x * blockDim.x;
    for (int e = blockIdx.x * blockDim.x + threadIdx.x; e < E; e += stride) {
        float2 p;
        p.x = __int_as_float(row[e]);
        p.y = w[e];
        pairs[ptr[col[e]] + pos[e]] = p;
    }
}

__global__ void degsum_kernel(const int* __restrict__ ptr, const float2* __restrict__ pairs,
                              float* __restrict__ dinv, int n) {
    int i = blockIdx.x * blockDim.x + threadIdx.x;
    if (i >= n) return;
    int beg = ptr[i], end = ptr[i + 1];
    float s = 0.f;
    for (int j = beg; j < end; ++j) s += pairs[j].y;
    dinv[i] = (s > 0.f) ? rsqrtf(s) : 0.f;
}

__global__ void fixup_kernel(float2* __restrict__ pairs, const float* __restrict__ dinv, int E) {
    int stride = gridDim.x * blockDim.x;
    for (int e = blockIdx.x * blockDim.x + threadIdx.x; e < E; e += stride) {
        float2 p = pairs[e];
        p.y *= dinv[__float_as_int(p.x)];
        pairs[e] = p;
    }
}

// =================== launch ===================

extern "C" void kernel_launch(void* const* d_in, const int* in_sizes, int n_in,
                              void* d_out, int out_size, void* d_ws, size_t ws_size,
                              hipStream_t stream) {
    const float* x      = (const float*)d_in[0];
    const int*   eidx   = (const int*)d_in[1];       // [2, E] int32
    const float* w      = (const float*)d_in[2];     // [E]
    const float* initW  = (const float*)d_in[3];     // [K]
    const float* weight = (const float*)d_in[4];     // [T-1, K]
    const float* rootW  = (const float*)d_in[5];     // [T, K]
    const float* bias   = (const float*)d_in[6];     // [T, K]
    const float* lin_w  = (const float*)d_in[7];     // [1]
    const float* lin_b  = (const float*)d_in[8];     // [1]
    float* outp = (float*)d_out;

    const int N = in_sizes[0];
    const int E = in_sizes[2];
    const int* row = eidx;
    const int* col = eidx + (size_t)E;

    const int TPB = 256;
    const int gridN = (N + TPB - 1) / TPB;
    const int gridE = 8192;
    const int nbuck = (N + BUCK_NODES - 1) >> RBITS;
    const int nScanB = (N + SCAN_BLOCK - 1) / SCAN_BLOCK;

    auto align16 = [](size_t v) { return (v + 15) & ~(size_t)15; };

    // ---- primary: radix-partition build ----
    {
        size_t off = 0;
        size_t tmpOff    = off; off += align16((size_t)E * 8);           // uint2[E]
        size_t pairsOff  = off; off += align16((size_t)E * 8);           // float2[E]
        size_t stAOff    = off; off += align16((size_t)N * 16);
        size_t stBOff    = off; off += align16((size_t)N * 16);
        size_t dinvOff   = off; off += align16((size_t)N * 4);
        size_t ptrOff    = off; off += align16((size_t)(N + 1) * 4);
        size_t cCntOff   = off; off += align16((size_t)(nbuck + 1) * 4);
        size_t cBaseOff  = off; off += align16((size_t)(nbuck + 1) * 4);
        size_t cCurOff   = off; off += align16((size_t)(nbuck + 1) * 4);
        size_t needed = off;

        if (ws_size >= needed && nbuck <= BUCK_NODES && N <= (1 << 20)) {
            char* wsb = (char*)d_ws;
            uint2*  tmp    = (uint2*)(wsb + tmpOff);
            float2* pairs  = (float2*)(wsb + pairsOff);
            float4* stA    = (float4*)(wsb + stAOff);
            float4* stB    = (float4*)(wsb + stBOff);
            float*  dinv   = (float*)(wsb + dinvOff);
            int*    ptr    = (int*)(wsb + ptrOff);
            int*    cCnt   = (int*)(wsb + cCntOff);
            int*    cBase  = (int*)(wsb + cBaseOff);
            int*    cCur   = (int*)(wsb + cCurOff);

            hipMemsetAsync(cCnt, 0, (size_t)(nbuck + 1) * 4, stream);

            coarse_count_kernel<<<1024, TPB, 0, stream>>>(col, cCnt, E, nbuck);
            coarse_scan_kernel<<<1, SCAN_BLOCK, 0, stream>>>(cCnt, cBase, cCur, nbuck, E);
            partition_kernel<<<1024, TPB, 0, stream>>>(row, col, w, cCur, tmp, E, nbuck);
            bucket_stats_kernel<<<nbuck, BUCK_NODES, 0, stream>>>(tmp, cBase, dinv, ptr, N, E, nbuck);
            bucket_scatter_kernel<<<nbuck, BUCK_NODES, 0, stream>>>(tmp, cBase, ptr, dinv, pairs, N, E, nbuck);

            pull0_kernel<<<gridN, TPB, 0, stream>>>(ptr, pairs, x, dinv, initW,
                                                    rootW + 0 * KK, bias + 0 * KK, stA, N);
            pullv_kernel<<<gridN, TPB, 0, stream>>>(ptr, pairs, stA, x, dinv, weight + 0 * KK,
                                                    rootW + 1 * KK, bias + 1 * KK, stB, N);
            pullv_kernel<<<gridN, TPB, 0, stream>>>(ptr, pairs, stB, x, dinv, weight + 1 * KK,
                                                    rootW + 2 * KK, bias + 2 * KK, stA, N);
            pull_final_kernel<<<gridN, TPB, 0, stream>>>(ptr, pairs, stA, x, dinv, weight + 2 * KK,
                                                         rootW + 3 * KK, bias + 3 * KK,
                                                         lin_w, lin_b, outp, N);
            return;
        }
    }

    // ---- fallback: round-3 path (1 atomic/edge build) ----
    {
        size_t off = 0;
        size_t pairsOff    = off; off += align16((size_t)E * 8);
        size_t posOff      = off; off += align16((size_t)E * 4);
        size_t stAOff      = off; off += align16((size_t)N * 16);
        size_t stBOff      = off; off += align16((size_t)N * 16);
        size_t dinvOff     = off; off += align16((size_t)N * 4);
        size_t cntOff      = off; off += align16((size_t)N * 4);
        size_t ptrOff      = off; off += align16((size_t)(N + 1) * 4);
        size_t partialsOff = off; off += align16((size_t)SCAN_BLOCK * 4);

        char* wsb = (char*)d_ws;
        float2* pairs = (float2*)(wsb + pairsOff);
        int*    pos   = (int*)(wsb + posOff);
        float4* stA   = (float4*)(wsb + stAOff);
        float4* stB   = (float4*)(wsb + stBOff);
        float*  dinv  = (float*)(wsb + dinvOff);
        int*    cnt   = (int*)(wsb + cntOff);
        int*    ptr   = (int*)(wsb + ptrOff);
        int*    parts = (int*)(wsb + partialsOff);

        hipMemsetAsync(cnt, 0, (size_t)N * 4, stream);

        count_pos_kernel<<<gridE, TPB, 0, stream>>>(col, cnt, pos, E);
        scan1_kernel<<<nScanB, SCAN_BLOCK, 0, stream>>>(cnt, ptr, parts, N);
        scan2_kernel<<<1, SCAN_BLOCK, 0, stream>>>(parts, nScanB);
        scan3_kernel<<<nScanB, SCAN_BLOCK, 0, stream>>>(ptr, nullptr, parts, N, E);
        scatter2_kernel<<<gridE, TPB, 0, stream>>>(row, col, w, ptr, pos, pairs, E);
        degsum_kernel<<<gridN, TPB, 0, stream>>>(ptr, pairs, dinv, N);
        fixup_kernel<<<gridE, TPB, 0, stream>>>(pairs, dinv, E);

        pull0_kernel<<<gridN, TPB, 0, stream>>>(ptr, pairs, x, dinv, initW,
                                                rootW + 0 * KK, bias + 0 * KK, stA, N);
        pullv_kernel<<<gridN, TPB, 0, stream>>>(ptr, pairs, stA, x, dinv, weight + 0 * KK,
                                                rootW + 1 * KK, bias + 1 * KK, stB, N);
        pullv_kernel<<<gridN, TPB, 0, stream>>>(ptr, pairs, stB, x, dinv, weight + 1 * KK,
                                                rootW + 2 * KK, bias + 2 * KK, stA, N);
        pull_final_kernel<<<gridN, TPB, 0, stream>>>(ptr, pairs, stA, x, dinv, weight + 2 * KK,
                                                     rootW + 3 * KK, bias + 3 * KK,
                                                     lin_w, lin_b, outp, N);
    }
}

// Round 5
// 3061.275 us; speedup vs baseline: 5.6529x; 1.8448x over previous
//
#include <hip/hip_runtime.h>

constexpr int KK = 3;
constexpr int SCAN_BLOCK = 1024;
constexpr int RBITS = 10;                 // nodes per coarse bucket = 1024
constexpr int BUCK_NODES = 1 << RBITS;

__device__ __forceinline__ float relu_(float v) { return fmaxf(v, 0.f); }

// =================== radix build ===================

__global__ void coarse_count_kernel(const int* __restrict__ col, int* __restrict__ coarseCnt,
                                    int E, int nbuck) {
    __shared__ int h[BUCK_NODES];
    for (int i = threadIdx.x; i < nbuck; i += blockDim.x) h[i] = 0;
    __syncthreads();
    long e0 = (long)blockIdx.x * E / gridDim.x;
    long e1 = (long)(blockIdx.x + 1) * E / gridDim.x;
    for (long e = e0 + threadIdx.x; e < e1; e += blockDim.x)
        atomicAdd(&h[col[e] >> RBITS], 1);
    __syncthreads();
    for (int i = threadIdx.x; i < nbuck; i += blockDim.x)
        if (h[i]) atomicAdd(&coarseCnt[i], h[i]);
}

__global__ void coarse_scan_kernel(const int* __restrict__ coarseCnt, int* __restrict__ coarseBase,
                                   int* __restrict__ coarseCur, int nbuck, int E) {
    __shared__ int sm[SCAN_BLOCK];
    int tid = threadIdx.x;
    int v = (tid < nbuck) ? coarseCnt[tid] : 0;
    sm[tid] = v;
    __syncthreads();
    for (int off = 1; off < SCAN_BLOCK; off <<= 1) {
        int t = (tid >= off) ? sm[tid - off] : 0;
        __syncthreads();
        sm[tid] += t;
        __syncthreads();
    }
    if (tid < nbuck) {
        int base = sm[tid] - v;
        coarseBase[tid] = base;
        coarseCur[tid] = base;
    }
    if (tid == 0) coarseBase[nbuck] = E;
}

// tmp[pos] = { (col_low<<20) | row , w_bits }   (needs N <= 2^20)
__global__ void partition_kernel(const int* __restrict__ row, const int* __restrict__ col,
                                 const float* __restrict__ w, int* __restrict__ coarseCur,
                                 uint2* __restrict__ tmp, int E, int nbuck) {
    __shared__ int h[BUCK_NODES];
    __shared__ int base[BUCK_NODES];
    for (int i = threadIdx.x; i < nbuck; i += blockDim.x) h[i] = 0;
    __syncthreads();
    long e0 = (long)blockIdx.x * E / gridDim.x;
    long e1 = (long)(blockIdx.x + 1) * E / gridDim.x;
    for (long e = e0 + threadIdx.x; e < e1; e += blockDim.x)
        atomicAdd(&h[col[e] >> RBITS], 1);
    __syncthreads();
    for (int i = threadIdx.x; i < nbuck; i += blockDim.x)
        base[i] = h[i] ? atomicAdd(&coarseCur[i], h[i]) : 0;
    __syncthreads();
    for (long e = e0 + threadIdx.x; e < e1; e += blockDim.x) {
        int c = col[e];
        int b = c >> RBITS;
        int pos = atomicAdd(&base[b], 1);
        uint2 t;
        t.x = ((unsigned)(c & (BUCK_NODES - 1)) << 20) | (unsigned)row[e];
        t.y = __float_as_uint(w[e]);
        tmp[pos] = t;
    }
}

// Per bucket: weighted-degree LDS hist -> dinv[node], xd[node] = dinv*x (sequential writes).
__global__ void bucket_deg_kernel(const uint2* __restrict__ tmp, const int* __restrict__ coarseBase,
                                  const float* __restrict__ x, float* __restrict__ dinv,
                                  float* __restrict__ xd, int N) {
    __shared__ float ws[BUCK_NODES];
    int b = blockIdx.x, tid = threadIdx.x;
    ws[tid] = 0.f;
    __syncthreads();
    int beg = coarseBase[b], end = coarseBase[b + 1];
    for (int j = beg + tid; j < end; j += blockDim.x) {
        uint2 t = tmp[j];
        atomicAdd(&ws[t.x >> 20], __uint_as_float(t.y));
    }
    __syncthreads();
    int node = (b << RBITS) + tid;
    if (node < N) {
        float s = ws[tid];
        float di = (s > 0.f) ? rsqrtf(s) : 0.f;
        dinv[node] = di;
        xd[node] = di * x[node];
    }
}

// =================== layer passes (bucket-streaming, LDS accumulate) ===================

// Layer 0: acc = sum w*xd[src]; one pass produces all 3 stacks.
__global__ void layer0_kernel(const uint2* __restrict__ tmp, const int* __restrict__ coarseBase,
                              const float* __restrict__ xd, const float* __restrict__ x,
                              const float* __restrict__ dinv,
                              const float* __restrict__ W, const float* __restrict__ V,
                              const float* __restrict__ b,
                              float* __restrict__ zd0, float* __restrict__ zd1,
                              float* __restrict__ zd2, int N) {
    __shared__ float acc[BUCK_NODES];
    int bk = blockIdx.x, tid = threadIdx.x;
    acc[tid] = 0.f;
    __syncthreads();
    int beg = coarseBase[bk], end = coarseBase[bk + 1];
    for (int j = beg + tid; j < end; j += blockDim.x) {
        uint2 t = tmp[j];
        atomicAdd(&acc[t.x >> 20], __uint_as_float(t.y) * xd[t.x & 0xFFFFF]);
    }
    __syncthreads();
    int node = (bk << RBITS) + tid;
    if (node < N) {
        float di = dinv[node];
        float s = di * acc[tid];
        float xi = x[node];
        zd0[node] = di * relu_(fmaf(W[0], s, fmaf(V[0], xi, b[0])));
        zd1[node] = di * relu_(fmaf(W[1], s, fmaf(V[1], xi, b[1])));
        zd2[node] = di * relu_(fmaf(W[2], s, fmaf(V[2], xi, b[2])));
    }
}

// MODE 0: zd_out = dinv*relu(...)        (mid layers)
// MODE 1: part   = relu(...)             (final layer, k=0)
// MODE 2: part  += relu(...)             (final layer, k=1)
// MODE 3: out    = sigmoid(lw*(part+relu(...))/3 + lb)   (final layer, k=2)
template <int MODE>
__global__ void layer_pass_kernel(const uint2* __restrict__ tmp, const int* __restrict__ coarseBase,
                                  const float* __restrict__ zd_in, const float* __restrict__ x,
                                  const float* __restrict__ dinv,
                                  const float* __restrict__ W, const float* __restrict__ V,
                                  const float* __restrict__ b,
                                  float* __restrict__ zd_out, float* __restrict__ part,
                                  const float* __restrict__ lin_w, const float* __restrict__ lin_b,
                                  float* __restrict__ outp, int N) {
    __shared__ float acc[BUCK_NODES];
    int bk = blockIdx.x, tid = threadIdx.x;
    acc[tid] = 0.f;
    __syncthreads();
    int beg = coarseBase[bk], end = coarseBase[bk + 1];
    for (int j = beg + tid; j < end; j += blockDim.x) {
        uint2 t = tmp[j];
        atomicAdd(&acc[t.x >> 20], __uint_as_float(t.y) * zd_in[t.x & 0xFFFFF]);
    }
    __syncthreads();
    int node = (bk << RBITS) + tid;
    if (node < N) {
        float di = dinv[node];
        float s = di * acc[tid];
        float h = relu_(fmaf(W[0], s, fmaf(V[0], x[node], b[0])));
        if (MODE == 0) {
            zd_out[node] = di * h;
        } else if (MODE == 1) {
            part[node] = h;
        } else if (MODE == 2) {
            part[node] += h;
        } else {
            float m = (part[node] + h) * (1.f / 3.f);
            float z = fmaf(lin_w[0], m, lin_b[0]);
            outp[node] = 1.f / (1.f + __expf(-z));
        }
    }
}

// =================== fallback (round-3 path, proven) ===================

__global__ void count_pos_kernel(const int* __restrict__ col, int* __restrict__ cnt,
                                 int* __restrict__ pos, int E) {
    int stride = gridDim.x * blockDim.x;
    for (int e = blockIdx.x * blockDim.x + threadIdx.x; e < E; e += stride)
        pos[e] = atomicAdd(&cnt[col[e]], 1);
}

__global__ void scan1_kernel(const int* __restrict__ cnt, int* __restrict__ ptr,
                             int* __restrict__ partials, int n) {
    __shared__ int sm[SCAN_BLOCK];
    int i = blockIdx.x * SCAN_BLOCK + threadIdx.x;
    int v = (i < n) ? cnt[i] : 0;
    sm[threadIdx.x] = v;
    __syncthreads();
    for (int off = 1; off < SCAN_BLOCK; off <<= 1) {
        int t = (threadIdx.x >= (unsigned)off) ? sm[threadIdx.x - off] : 0;
        __syncthreads();
        sm[threadIdx.x] += t;
        __syncthreads();
    }
    if (i < n) ptr[i] = sm[threadIdx.x] - v;
    if (threadIdx.x == SCAN_BLOCK - 1) partials[blockIdx.x] = sm[threadIdx.x];
}

__global__ void scan2_kernel(int* __restrict__ partials, int np) {
    __shared__ int sm[SCAN_BLOCK];
    int v = (threadIdx.x < (unsigned)np) ? partials[threadIdx.x] : 0;
    sm[threadIdx.x] = v;
    __syncthreads();
    for (int off = 1; off < SCAN_BLOCK; off <<= 1) {
        int t = (threadIdx.x >= (unsigned)off) ? sm[threadIdx.x - off] : 0;
        __syncthreads();
        sm[threadIdx.x] += t;
        __syncthreads();
    }
    if (threadIdx.x < (unsigned)np) partials[threadIdx.x] = sm[threadIdx.x] - v;
}

__global__ void scan3_kernel(int* __restrict__ ptr, int* __restrict__ cur,
                             const int* __restrict__ partials, int n, int E) {
    int i = blockIdx.x * SCAN_BLOCK + threadIdx.x;
    if (i < n) {
        int v = ptr[i] + partials[blockIdx.x];
        ptr[i] = v;
        if (cur) cur[i] = v;
    }
    if (i == 0) ptr[n] = E;
}

__global__ void scatter2_kernel(const int* __restrict__ row, const int* __restrict__ col,
                                const float* __restrict__ w, const int* __restrict__ ptr,
                                const int* __restrict__ pos, float2* __restrict__ pairs, int E) {
    int stride = gridDim.x * blockDim.x;
    for (int e = blockIdx.x * blockDim.x + threadIdx.x; e < E; e += stride) {
        float2 p;
        p.x = __int_as_float(row[e]);
        p.y = w[e];
        pairs[ptr[col[e]] + pos[e]] = p;
    }
}

__global__ void degsum_kernel(const int* __restrict__ ptr, const float2* __restrict__ pairs,
                              float* __restrict__ dinv, int n) {
    int i = blockIdx.x * blockDim.x + threadIdx.x;
    if (i >= n) return;
    int beg = ptr[i], end = ptr[i + 1];
    float s = 0.f;
    for (int j = beg; j < end; ++j) s += pairs[j].y;
    dinv[i] = (s > 0.f) ? rsqrtf(s) : 0.f;
}

__global__ void fixup_kernel(float2* __restrict__ pairs, const float* __restrict__ dinv, int E) {
    int stride = gridDim.x * blockDim.x;
    for (int e = blockIdx.x * blockDim.x + threadIdx.x; e < E; e += stride) {
        float2 p = pairs[e];
        p.y *= dinv[__float_as_int(p.x)];
        pairs[e] = p;
    }
}

__global__ void pull0_kernel(const int* __restrict__ ptr, const float2* __restrict__ pairs,
                             const float* __restrict__ x, const float* __restrict__ dinv,
                             const float* __restrict__ W, const float* __restrict__ V,
                             const float* __restrict__ b, float4* __restrict__ st, int n) {
    int i = blockIdx.x * blockDim.x + threadIdx.x;
    if (i >= n) return;
    int beg = ptr[i], end = ptr[i + 1];
    float s = 0.f;
    for (int j = beg; j < end; ++j) {
        float2 p = pairs[j];
        s += p.y * x[__float_as_int(p.x)];
    }
    s *= dinv[i];
    float xi = x[i];
    float4 o;
    o.x = relu_(fmaf(W[0], s, fmaf(V[0], xi, b[0])));
    o.y = relu_(fmaf(W[1], s, fmaf(V[1], xi, b[1])));
    o.z = relu_(fmaf(W[2], s, fmaf(V[2], xi, b[2])));
    o.w = 0.f;
    st[i] = o;
}

__global__ void pullv_kernel(const int* __restrict__ ptr, const float2* __restrict__ pairs,
                             const float4* __restrict__ stIn, const float* __restrict__ x,
                             const float* __restrict__ dinv, const float* __restrict__ W,
                             const float* __restrict__ V, const float* __restrict__ b,
                             float4* __restrict__ stOut, int n) {
    int i = blockIdx.x * blockDim.x + threadIdx.x;
    if (i >= n) return;
    int beg = ptr[i], end = ptr[i + 1];
    float sx = 0.f, sy = 0.f, sz = 0.f;
    for (int j = beg; j < end; ++j) {
        float2 p = pairs[j];
        float4 v = stIn[__float_as_int(p.x)];
        sx = fmaf(p.y, v.x, sx);
        sy = fmaf(p.y, v.y, sy);
        sz = fmaf(p.y, v.z, sz);
    }
    float di = dinv[i], xi = x[i];
    float4 o;
    o.x = relu_(fmaf(W[0], sx * di, fmaf(V[0], xi, b[0])));
    o.y = relu_(fmaf(W[1], sy * di, fmaf(V[1], xi, b[1])));
    o.z = relu_(fmaf(W[2], sz * di, fmaf(V[2], xi, b[2])));
    o.w = 0.f;
    stOut[i] = o;
}

__global__ void pull_final_kernel(const int* __restrict__ ptr, const float2* __restrict__ pairs,
                                  const float4* __restrict__ stIn, const float* __restrict__ x,
                                  const float* __restrict__ dinv, const float* __restrict__ W,
                                  const float* __restrict__ V, const float* __restrict__ b,
                                  const float* __restrict__ lin_w, const float* __restrict__ lin_b,
                                  float* __restrict__ outp, int n) {
    int i = blockIdx.x * blockDim.x + threadIdx.x;
    if (i >= n) return;
    int beg = ptr[i], end = ptr[i + 1];
    float sx = 0.f, sy = 0.f, sz = 0.f;
    for (int j = beg; j < end; ++j) {
        float2 p = pairs[j];
        float4 v = stIn[__float_as_int(p.x)];
        sx = fmaf(p.y, v.x, sx);
        sy = fmaf(p.y, v.y, sy);
        sz = fmaf(p.y, v.z, sz);
    }
    float di = dinv[i], xi = x[i];
    float ox = relu_(fmaf(W[0], sx * di, fmaf(V[0], xi, b[0])));
    float oy = relu_(fmaf(W[1], sy * di, fmaf(V[1], xi, b[1])));
    float oz = relu_(fmaf(W[2], sz * di, fmaf(V[2], xi, b[2])));
    float m = (ox + oy + oz) * (1.f / 3.f);
    float z = fmaf(lin_w[0], m, lin_b[0]);
    outp[i] = 1.f / (1.f + __expf(-z));
}

// =================== launch ===================

extern "C" void kernel_launch(void* const* d_in, const int* in_sizes, int n_in,
                              void* d_out, int out_size, void* d_ws, size_t ws_size,
                              hipStream_t stream) {
    const float* x      = (const float*)d_in[0];
    const int*   eidx   = (const int*)d_in[1];
    const float* w      = (const float*)d_in[2];
    const float* initW  = (const float*)d_in[3];
    const float* weight = (const float*)d_in[4];
    const float* rootW  = (const float*)d_in[5];
    const float* bias   = (const float*)d_in[6];
    const float* lin_w  = (const float*)d_in[7];
    const float* lin_b  = (const float*)d_in[8];
    float* outp = (float*)d_out;

    const int N = in_sizes[0];
    const int E = in_sizes[2];
    const int* row = eidx;
    const int* col = eidx + (size_t)E;

    const int TPB = 256;
    const int gridN = (N + TPB - 1) / TPB;
    const int nbuck = (N + BUCK_NODES - 1) >> RBITS;
    const int nScanB = (N + SCAN_BLOCK - 1) / SCAN_BLOCK;

    auto align16 = [](size_t v) { return (v + 15) & ~(size_t)15; };

    // ---- primary: bucket-stream path ----
    {
        size_t off = 0;
        size_t tmpOff   = off; off += align16((size_t)E * 8);            // uint2[E]
        size_t zdA0Off  = off; off += align16((size_t)N * 4);
        size_t zdA1Off  = off; off += align16((size_t)N * 4);
        size_t zdA2Off  = off; off += align16((size_t)N * 4);
        size_t zdB0Off  = off; off += align16((size_t)N * 4);
        size_t zdB1Off  = off; off += align16((size_t)N * 4);
        size_t zdB2Off  = off; off += align16((size_t)N * 4);
        size_t dinvOff  = off; off += align16((size_t)N * 4);
        size_t xdOff    = off; off += align16((size_t)N * 4);
        size_t partOff  = off; off += align16((size_t)N * 4);
        size_t cCntOff  = off; off += align16((size_t)(nbuck + 1) * 4);
        size_t cBaseOff = off; off += align16((size_t)(nbuck + 1) * 4);
        size_t cCurOff  = off; off += align16((size_t)(nbuck + 1) * 4);
        size_t needed = off;

        if (ws_size >= needed && nbuck <= SCAN_BLOCK && N <= (1 << 20)) {
            char* wsb = (char*)d_ws;
            uint2* tmp   = (uint2*)(wsb + tmpOff);
            float* zdA[3] = {(float*)(wsb + zdA0Off), (float*)(wsb + zdA1Off), (float*)(wsb + zdA2Off)};
            float* zdB[3] = {(float*)(wsb + zdB0Off), (float*)(wsb + zdB1Off), (float*)(wsb + zdB2Off)};
            float* dinv  = (float*)(wsb + dinvOff);
            float* xd    = (float*)(wsb + xdOff);
            float* part  = (float*)(wsb + partOff);
            int* cCnt    = (int*)(wsb + cCntOff);
            int* cBase   = (int*)(wsb + cBaseOff);
            int* cCur    = (int*)(wsb + cCurOff);

            hipMemsetAsync(cCnt, 0, (size_t)(nbuck + 1) * 4, stream);

            coarse_count_kernel<<<1024, TPB, 0, stream>>>(col, cCnt, E, nbuck);
            coarse_scan_kernel<<<1, SCAN_BLOCK, 0, stream>>>(cCnt, cBase, cCur, nbuck, E);
            partition_kernel<<<1024, TPB, 0, stream>>>(row, col, w, cCur, tmp, E, nbuck);
            bucket_deg_kernel<<<nbuck, BUCK_NODES, 0, stream>>>(tmp, cBase, x, dinv, xd, N);

            // layer 0 (one pass, all 3 stacks)
            layer0_kernel<<<nbuck, BUCK_NODES, 0, stream>>>(tmp, cBase, xd, x, dinv, initW,
                                                            rootW + 0 * KK, bias + 0 * KK,
                                                            zdA[0], zdA[1], zdA[2], N);
            // layers 1,2 (per-stack passes, ping-pong)
            for (int k = 0; k < KK; ++k)
                layer_pass_kernel<0><<<nbuck, BUCK_NODES, 0, stream>>>(
                    tmp, cBase, zdA[k], x, dinv, weight + 0 * KK + k, rootW + 1 * KK + k,
                    bias + 1 * KK + k, zdB[k], nullptr, nullptr, nullptr, nullptr, N);
            for (int k = 0; k < KK; ++k)
                layer_pass_kernel<0><<<nbuck, BUCK_NODES, 0, stream>>>(
                    tmp, cBase, zdB[k], x, dinv, weight + 1 * KK + k, rootW + 2 * KK + k,
                    bias + 2 * KK + k, zdA[k], nullptr, nullptr, nullptr, nullptr, N);
            // layer 3 fused with mean/linear/sigmoid
            layer_pass_kernel<1><<<nbuck, BUCK_NODES, 0, stream>>>(
                tmp, cBase, zdA[0], x, dinv, weight + 2 * KK + 0, rootW + 3 * KK + 0,
                bias + 3 * KK + 0, nullptr, part, nullptr, nullptr, nullptr, N);
            layer_pass_kernel<2><<<nbuck, BUCK_NODES, 0, stream>>>(
                tmp, cBase, zdA[1], x, dinv, weight + 2 * KK + 1, rootW + 3 * KK + 1,
                bias + 3 * KK + 1, nullptr, part, nullptr, nullptr, nullptr, N);
            layer_pass_kernel<3><<<nbuck, BUCK_NODES, 0, stream>>>(
                tmp, cBase, zdA[2], x, dinv, weight + 2 * KK + 2, rootW + 3 * KK + 2,
                bias + 3 * KK + 2, nullptr, part, lin_w, lin_b, outp, N);
            return;
        }
    }

    // ---- fallback: round-3 CSR-pull path ----
    {
        size_t off = 0;
        size_t pairsOff    = off; off += align16((size_t)E * 8);
        size_t posOff      = off; off += align16((size_t)E * 4);
        size_t stAOff      = off; off += align16((size_t)N * 16);
        size_t stBOff      = off; off += align16((size_t)N * 16);
        size_t dinvOff     = off; off += align16((size_t)N * 4);
        size_t cntOff      = off; off += align16((size_t)N * 4);
        size_t ptrOff      = off; off += align16((size_t)(N + 1) * 4);
        size_t partialsOff = off; off += align16((size_t)SCAN_BLOCK * 4);

        char* wsb = (char*)d_ws;
        float2* pairs = (float2*)(wsb + pairsOff);
        int*    pos   = (int*)(wsb + posOff);
        float4* stA   = (float4*)(wsb + stAOff);
        float4* stB   = (float4*)(wsb + stBOff);
        float*  dinv  = (float*)(wsb + dinvOff);
        int*    cnt   = (int*)(wsb + cntOff);
        int*    ptr   = (int*)(wsb + ptrOff);
        int*    parts = (int*)(wsb + partialsOff);

        hipMemsetAsync(cnt, 0, (size_t)N * 4, stream);

        count_pos_kernel<<<8192, TPB, 0, stream>>>(col, cnt, pos, E);
        scan1_kernel<<<nScanB, SCAN_BLOCK, 0, stream>>>(cnt, ptr, parts, N);
        scan2_kernel<<<1, SCAN_BLOCK, 0, stream>>>(parts, nScanB);
        scan3_kernel<<<nScanB, SCAN_BLOCK, 0, stream>>>(ptr, nullptr, parts, N, E);
        scatter2_kernel<<<8192, TPB, 0, stream>>>(row, col, w, ptr, pos, pairs, E);
        degsum_kernel<<<gridN, TPB, 0, stream>>>(ptr, pairs, dinv, N);
        fixup_kernel<<<8192, TPB, 0, stream>>>(pairs, dinv, E);

        pull0_kernel<<<gridN, TPB, 0, stream>>>(ptr, pairs, x, dinv, initW,
                                                rootW + 0 * KK, bias + 0 * KK, stA, N);
        pullv_kernel<<<gridN, TPB, 0, stream>>>(ptr, pairs, stA, x, dinv, weight + 0 * KK,
                                                rootW + 1 * KK, bias + 1 * KK, stB, N);
        pullv_kernel<<<gridN, TPB, 0, stream>>>(ptr, pairs, stB, x, dinv, weight + 1 * KK,
                                                rootW + 2 * KK, bias + 2 * KK, stA, N);
        pull_final_kernel<<<gridN, TPB, 0, stream>>>(ptr, pairs, stA, x, dinv, weight + 2 * KK,
                                                     rootW + 3 * KK, bias + 3 * KK,
                                                     lin_w, lin_b, outp, N);
    }
}

// Round 6
// 3025.684 us; speedup vs baseline: 5.7194x; 1.0118x over previous
//
#include <hip/hip_runtime.h>

constexpr int KK = 3;
constexpr int SCAN_BLOCK = 1024;
constexpr int RBITS = 10;                 // nodes per coarse bucket = 1024
constexpr int BUCK_NODES = 1 << RBITS;
constexpr int NB = 256;                   // partition blocks (must equal colscan blockDim)
constexpr int PB_T = 1024;                // partition threads per block

__device__ __forceinline__ float relu_(float v) { return fmaxf(v, 0.f); }

__device__ __forceinline__ void nt_edge(const unsigned long long* tp, long j,
                                        int& cl, int& src, float& wv) {
    unsigned long long v = __builtin_nontemporal_load(tp + j);
    unsigned key = (unsigned)(v & 0xFFFFFFFFull);
    wv = __uint_as_float((unsigned)(v >> 32));
    cl = (int)(key >> 20);
    src = (int)(key & 0xFFFFF);
}

// =================== deterministic two-phase partition ===================

// Pass A: per-block histogram of coarse buckets -> blockHist[block][bucket]
__global__ void hist_kernel(const int* __restrict__ col, int* __restrict__ blockHist,
                            int E, int nbuck) {
    __shared__ int h[BUCK_NODES];
    for (int i = threadIdx.x; i < nbuck; i += blockDim.x) h[i] = 0;
    __syncthreads();
    long e0 = (long)blockIdx.x * E / gridDim.x;
    long e1 = (long)(blockIdx.x + 1) * E / gridDim.x;
    for (long e = e0 + threadIdx.x; e < e1; e += blockDim.x)
        atomicAdd(&h[__builtin_nontemporal_load(&col[e]) >> RBITS], 1);
    __syncthreads();
    int* dst = blockHist + (size_t)blockIdx.x * nbuck;
    for (int i = threadIdx.x; i < nbuck; i += blockDim.x) dst[i] = h[i];
}

// Column scan: for each bucket, exclusive prefix over the NB blocks.
// blockHist becomes blockOff; total[i] = bucket count. blockDim.x == NB.
__global__ void colscan_kernel(int* __restrict__ blockHist, int* __restrict__ total, int nbuck) {
    __shared__ int sm[NB];
    int i = blockIdx.x, tid = threadIdx.x;
    int v = blockHist[(size_t)tid * nbuck + i];
    sm[tid] = v;
    __syncthreads();
    for (int off = 1; off < NB; off <<= 1) {
        int t = (tid >= off) ? sm[tid - off] : 0;
        __syncthreads();
        sm[tid] += t;
        __syncthreads();
    }
    blockHist[(size_t)tid * nbuck + i] = sm[tid] - v;   // exclusive over blocks
    if (tid == NB - 1) total[i] = sm[tid];
}

// Exclusive scan of totals -> cBase (single block; nbuck <= 1024).
__global__ void coarse_scan_kernel(const int* __restrict__ total, int* __restrict__ cBase,
                                   int nbuck, int E) {
    __shared__ int sm[SCAN_BLOCK];
    int tid = threadIdx.x;
    int v = (tid < nbuck) ? total[tid] : 0;
    sm[tid] = v;
    __syncthreads();
    for (int off = 1; off < SCAN_BLOCK; off <<= 1) {
        int t = (tid >= off) ? sm[tid - off] : 0;
        __syncthreads();
        sm[tid] += t;
        __syncthreads();
    }
    if (tid < nbuck) cBase[tid] = sm[tid] - v;
    if (tid == 0) cBase[nbuck] = E;
}

// Pass B: scatter with LDS cursors only (no global atomics).
// tmp[pos] = { (col_low<<20) | row , w_bits }   (needs N <= 2^20)
__global__ void partition2_kernel(const int* __restrict__ row, const int* __restrict__ col,
                                  const float* __restrict__ w, const int* __restrict__ cBase,
                                  const int* __restrict__ blockOff, uint2* __restrict__ tmp,
                                  int E, int nbuck) {
    __shared__ int cur[BUCK_NODES];
    const int* boff = blockOff + (size_t)blockIdx.x * nbuck;
    for (int i = threadIdx.x; i < nbuck; i += blockDim.x)
        cur[i] = cBase[i] + boff[i];
    __syncthreads();
    long e0 = (long)blockIdx.x * E / gridDim.x;
    long e1 = (long)(blockIdx.x + 1) * E / gridDim.x;
    for (long e = e0 + threadIdx.x; e < e1; e += blockDim.x) {
        int c = __builtin_nontemporal_load(&col[e]);
        int b = c >> RBITS;
        int pos = atomicAdd(&cur[b], 1);
        uint2 t;
        t.x = ((unsigned)(c & (BUCK_NODES - 1)) << 20) |
              (unsigned)__builtin_nontemporal_load(&row[e]);
        t.y = __float_as_uint(__builtin_nontemporal_load(&w[e]));
        tmp[pos] = t;
    }
}

// Per bucket: weighted-degree LDS hist -> dinv[node], xd[node] = dinv*x.
__global__ void bucket_deg_kernel(const uint2* __restrict__ tmp, const int* __restrict__ coarseBase,
                                  const float* __restrict__ x, float* __restrict__ dinv,
                                  float* __restrict__ xd, int N) {
    __shared__ float ws[BUCK_NODES];
    int b = blockIdx.x, tid = threadIdx.x;
    ws[tid] = 0.f;
    __syncthreads();
    const unsigned long long* tp = (const unsigned long long*)tmp;
    int beg = coarseBase[b], end = coarseBase[b + 1];
    for (long j = beg + tid; j < end; j += blockDim.x) {
        int cl, src; float wv;
        nt_edge(tp, j, cl, src, wv);
        atomicAdd(&ws[cl], wv);
    }
    __syncthreads();
    int node = (b << RBITS) + tid;
    if (node < N) {
        float s = ws[tid];
        float di = (s > 0.f) ? rsqrtf(s) : 0.f;
        dinv[node] = di;
        xd[node] = di * x[node];
    }
}

// =================== layer passes (bucket-streaming, LDS accumulate) ===================

__global__ void layer0_kernel(const uint2* __restrict__ tmp, const int* __restrict__ coarseBase,
                              const float* __restrict__ xd, const float* __restrict__ x,
                              const float* __restrict__ dinv,
                              const float* __restrict__ W, const float* __restrict__ V,
                              const float* __restrict__ b,
                              float* __restrict__ zd0, float* __restrict__ zd1,
                              float* __restrict__ zd2, int N) {
    __shared__ float acc[BUCK_NODES];
    int bk = blockIdx.x, tid = threadIdx.x;
    acc[tid] = 0.f;
    __syncthreads();
    const unsigned long long* tp = (const unsigned long long*)tmp;
    int beg = coarseBase[bk], end = coarseBase[bk + 1];
    for (long j = beg + tid; j < end; j += blockDim.x) {
        int cl, src; float wv;
        nt_edge(tp, j, cl, src, wv);
        atomicAdd(&acc[cl], wv * xd[src]);
    }
    __syncthreads();
    int node = (bk << RBITS) + tid;
    if (node < N) {
        float di = dinv[node];
        float s = di * acc[tid];
        float xi = x[node];
        zd0[node] = di * relu_(fmaf(W[0], s, fmaf(V[0], xi, b[0])));
        zd1[node] = di * relu_(fmaf(W[1], s, fmaf(V[1], xi, b[1])));
        zd2[node] = di * relu_(fmaf(W[2], s, fmaf(V[2], xi, b[2])));
    }
}

// MODE 0: zd_out = dinv*relu(...)   MODE 1: part = relu(...)
// MODE 2: part += relu(...)         MODE 3: out = sigmoid(lw*(part+relu(...))/3 + lb)
template <int MODE>
__global__ void layer_pass_kernel(const uint2* __restrict__ tmp, const int* __restrict__ coarseBase,
                                  const float* __restrict__ zd_in, const float* __restrict__ x,
                                  const float* __restrict__ dinv,
                                  const float* __restrict__ W, const float* __restrict__ V,
                                  const float* __restrict__ b,
                                  float* __restrict__ zd_out, float* __restrict__ part,
                                  const float* __restrict__ lin_w, const float* __restrict__ lin_b,
                                  float* __restrict__ outp, int N) {
    __shared__ float acc[BUCK_NODES];
    int bk = blockIdx.x, tid = threadIdx.x;
    acc[tid] = 0.f;
    __syncthreads();
    const unsigned long long* tp = (const unsigned long long*)tmp;
    int beg = coarseBase[bk], end = coarseBase[bk + 1];
    for (long j = beg + tid; j < end; j += blockDim.x) {
        int cl, src; float wv;
        nt_edge(tp, j, cl, src, wv);
        atomicAdd(&acc[cl], wv * zd_in[src]);
    }
    __syncthreads();
    int node = (bk << RBITS) + tid;
    if (node < N) {
        float di = dinv[node];
        float s = di * acc[tid];
        float h = relu_(fmaf(W[0], s, fmaf(V[0], x[node], b[0])));
        if (MODE == 0) {
            zd_out[node] = di * h;
        } else if (MODE == 1) {
            part[node] = h;
        } else if (MODE == 2) {
            part[node] += h;
        } else {
            float m = (part[node] + h) * (1.f / 3.f);
            float z = fmaf(lin_w[0], m, lin_b[0]);
            outp[node] = 1.f / (1.f + __expf(-z));
        }
    }
}

// =================== fallback (round-3 path, proven) ===================

__global__ void count_pos_kernel(const int* __restrict__ col, int* __restrict__ cnt,
                                 int* __restrict__ pos, int E) {
    int stride = gridDim.x * blockDim.x;
    for (int e = blockIdx.x * blockDim.x + threadIdx.x; e < E; e += stride)
        pos[e] = atomicAdd(&cnt[col[e]], 1);
}

__global__ void scan1_kernel(const int* __restrict__ cnt, int* __restrict__ ptr,
                             int* __restrict__ partials, int n) {
    __shared__ int sm[SCAN_BLOCK];
    int i = blockIdx.x * SCAN_BLOCK + threadIdx.x;
    int v = (i < n) ? cnt[i] : 0;
    sm[threadIdx.x] = v;
    __syncthreads();
    for (int off = 1; off < SCAN_BLOCK; off <<= 1) {
        int t = (threadIdx.x >= (unsigned)off) ? sm[threadIdx.x - off] : 0;
        __syncthreads();
        sm[threadIdx.x] += t;
        __syncthreads();
    }
    if (i < n) ptr[i] = sm[threadIdx.x] - v;
    if (threadIdx.x == SCAN_BLOCK - 1) partials[blockIdx.x] = sm[threadIdx.x];
}

__global__ void scan2_kernel(int* __restrict__ partials, int np) {
    __shared__ int sm[SCAN_BLOCK];
    int v = (threadIdx.x < (unsigned)np) ? partials[threadIdx.x] : 0;
    sm[threadIdx.x] = v;
    __syncthreads();
    for (int off = 1; off < SCAN_BLOCK; off <<= 1) {
        int t = (threadIdx.x >= (unsigned)off) ? sm[threadIdx.x - off] : 0;
        __syncthreads();
        sm[threadIdx.x] += t;
        __syncthreads();
    }
    if (threadIdx.x < (unsigned)np) partials[threadIdx.x] = sm[threadIdx.x] - v;
}

__global__ void scan3_kernel(int* __restrict__ ptr, int* __restrict__ cur,
                             const int* __restrict__ partials, int n, int E) {
    int i = blockIdx.x * SCAN_BLOCK + threadIdx.x;
    if (i < n) {
        int v = ptr[i] + partials[blockIdx.x];
        ptr[i] = v;
        if (cur) cur[i] = v;
    }
    if (i == 0) ptr[n] = E;
}

__global__ void scatter2_kernel(const int* __restrict__ row, const int* __restrict__ col,
                                const float* __restrict__ w, const int* __restrict__ ptr,
                                const int* __restrict__ pos, float2* __restrict__ pairs, int E) {
    int stride = gridDim.x * blockDim.x;
    for (int e = blockIdx.x * blockDim.x + threadIdx.x; e < E; e += stride) {
        float2 p;
        p.x = __int_as_float(row[e]);
        p.y = w[e];
        pairs[ptr[col[e]] + pos[e]] = p;
    }
}

__global__ void degsum_kernel(const int* __restrict__ ptr, const float2* __restrict__ pairs,
                              float* __restrict__ dinv, int n) {
    int i = blockIdx.x * blockDim.x + threadIdx.x;
    if (i >= n) return;
    int beg = ptr[i], end = ptr[i + 1];
    float s = 0.f;
    for (int j = beg; j < end; ++j) s += pairs[j].y;
    dinv[i] = (s > 0.f) ? rsqrtf(s) : 0.f;
}

__global__ void fixup_kernel(float2* __restrict__ pairs, const float* __restrict__ dinv, int E) {
    int stride = gridDim.x * blockDim.x;
    for (int e = blockIdx.x * blockDim.x + threadIdx.x; e < E; e += stride) {
        float2 p = pairs[e];
        p.y *= dinv[__float_as_int(p.x)];
        pairs[e] = p;
    }
}

__global__ void pull0_kernel(const int* __restrict__ ptr, const float2* __restrict__ pairs,
                             const float* __restrict__ x, const float* __restrict__ dinv,
                             const float* __restrict__ W, const float* __restrict__ V,
                             const float* __restrict__ b, float4* __restrict__ st, int n) {
    int i = blockIdx.x * blockDim.x + threadIdx.x;
    if (i >= n) return;
    int beg = ptr[i], end = ptr[i + 1];
    float s = 0.f;
    for (int j = beg; j < end; ++j) {
        float2 p = pairs[j];
        s += p.y * x[__float_as_int(p.x)];
    }
    s *= dinv[i];
    float xi = x[i];
    float4 o;
    o.x = relu_(fmaf(W[0], s, fmaf(V[0], xi, b[0])));
    o.y = relu_(fmaf(W[1], s, fmaf(V[1], xi, b[1])));
    o.z = relu_(fmaf(W[2], s, fmaf(V[2], xi, b[2])));
    o.w = 0.f;
    st[i] = o;
}

__global__ void pullv_kernel(const int* __restrict__ ptr, const float2* __restrict__ pairs,
                             const float4* __restrict__ stIn, const float* __restrict__ x,
                             const float* __restrict__ dinv, const float* __restrict__ W,
                             const float* __restrict__ V, const float* __restrict__ b,
                             float4* __restrict__ stOut, int n) {
    int i = blockIdx.x * blockDim.x + threadIdx.x;
    if (i >= n) return;
    int beg = ptr[i], end = ptr[i + 1];
    float sx = 0.f, sy = 0.f, sz = 0.f;
    for (int j = beg; j < end; ++j) {
        float2 p = pairs[j];
        float4 v = stIn[__float_as_int(p.x)];
        sx = fmaf(p.y, v.x, sx);
        sy = fmaf(p.y, v.y, sy);
        sz = fmaf(p.y, v.z, sz);
    }
    float di = dinv[i], xi = x[i];
    float4 o;
    o.x = relu_(fmaf(W[0], sx * di, fmaf(V[0], xi, b[0])));
    o.y = relu_(fmaf(W[1], sy * di, fmaf(V[1], xi, b[1])));
    o.z = relu_(fmaf(W[2], sz * di, fmaf(V[2], xi, b[2])));
    o.w = 0.f;
    stOut[i] = o;
}

__global__ void pull_final_kernel(const int* __restrict__ ptr, const float2* __restrict__ pairs,
                                  const float4* __restrict__ stIn, const float* __restrict__ x,
                                  const float* __restrict__ dinv, const float* __restrict__ W,
                                  const float* __restrict__ V, const float* __restrict__ b,
                                  const float* __restrict__ lin_w, const float* __restrict__ lin_b,
                                  float* __restrict__ outp, int n) {
    int i = blockIdx.x * blockDim.x + threadIdx.x;
    if (i >= n) return;
    int beg = ptr[i], end = ptr[i + 1];
    float sx = 0.f, sy = 0.f, sz = 0.f;
    for (int j = beg; j < end; ++j) {
        float2 p = pairs[j];
        float4 v = stIn[__float_as_int(p.x)];
        sx = fmaf(p.y, v.x, sx);
        sy = fmaf(p.y, v.y, sy);
        sz = fmaf(p.y, v.z, sz);
    }
    float di = dinv[i], xi = x[i];
    float ox = relu_(fmaf(W[0], sx * di, fmaf(V[0], xi, b[0])));
    float oy = relu_(fmaf(W[1], sy * di, fmaf(V[1], xi, b[1])));
    float oz = relu_(fmaf(W[2], sz * di, fmaf(V[2], xi, b[2])));
    float m = (ox + oy + oz) * (1.f / 3.f);
    float z = fmaf(lin_w[0], m, lin_b[0]);
    outp[i] = 1.f / (1.f + __expf(-z));
}

// =================== launch ===================

extern "C" void kernel_launch(void* const* d_in, const int* in_sizes, int n_in,
                              void* d_out, int out_size, void* d_ws, size_t ws_size,
                              hipStream_t stream) {
    const float* x      = (const float*)d_in[0];
    const int*   eidx   = (const int*)d_in[1];
    const float* w      = (const float*)d_in[2];
    const float* initW  = (const float*)d_in[3];
    const float* weight = (const float*)d_in[4];
    const float* rootW  = (const float*)d_in[5];
    const float* bias   = (const float*)d_in[6];
    const float* lin_w  = (const float*)d_in[7];
    const float* lin_b  = (const float*)d_in[8];
    float* outp = (float*)d_out;

    const int N = in_sizes[0];
    const int E = in_sizes[2];
    const int* row = eidx;
    const int* col = eidx + (size_t)E;

    const int TPB = 256;
    const int gridN = (N + TPB - 1) / TPB;
    const int nbuck = (N + BUCK_NODES - 1) >> RBITS;
    const int nScanB = (N + SCAN_BLOCK - 1) / SCAN_BLOCK;

    auto align16 = [](size_t v) { return (v + 15) & ~(size_t)15; };

    // ---- primary: deterministic-partition bucket-stream path ----
    {
        size_t off = 0;
        size_t tmpOff   = off; off += align16((size_t)E * 8);            // uint2[E]
        size_t bhOff    = off; off += align16((size_t)NB * nbuck * 4);   // blockHist/blockOff
        size_t totOff   = off; off += align16((size_t)nbuck * 4);
        size_t cBaseOff = off; off += align16((size_t)(nbuck + 1) * 4);
        size_t zdA0Off  = off; off += align16((size_t)N * 4);
        size_t zdA1Off  = off; off += align16((size_t)N * 4);
        size_t zdA2Off  = off; off += align16((size_t)N * 4);
        size_t zdB0Off  = off; off += align16((size_t)N * 4);
        size_t zdB1Off  = off; off += align16((size_t)N * 4);
        size_t zdB2Off  = off; off += align16((size_t)N * 4);
        size_t dinvOff  = off; off += align16((size_t)N * 4);
        size_t xdOff    = off; off += align16((size_t)N * 4);
        size_t partOff  = off; off += align16((size_t)N * 4);
        size_t needed = off;

        if (ws_size >= needed && nbuck <= SCAN_BLOCK && N <= (1 << 20)) {
            char* wsb = (char*)d_ws;
            uint2* tmp    = (uint2*)(wsb + tmpOff);
            int*   bh     = (int*)(wsb + bhOff);
            int*   total  = (int*)(wsb + totOff);
            int*   cBase  = (int*)(wsb + cBaseOff);
            float* zdA[3] = {(float*)(wsb + zdA0Off), (float*)(wsb + zdA1Off), (float*)(wsb + zdA2Off)};
            float* zdB[3] = {(float*)(wsb + zdB0Off), (float*)(wsb + zdB1Off), (float*)(wsb + zdB2Off)};
            float* dinv   = (float*)(wsb + dinvOff);
            float* xd     = (float*)(wsb + xdOff);
            float* part   = (float*)(wsb + partOff);

            // deterministic two-phase partition (no global atomics)
            hist_kernel<<<NB, PB_T, 0, stream>>>(col, bh, E, nbuck);
            colscan_kernel<<<nbuck, NB, 0, stream>>>(bh, total, nbuck);
            coarse_scan_kernel<<<1, SCAN_BLOCK, 0, stream>>>(total, cBase, nbuck, E);
            partition2_kernel<<<NB, PB_T, 0, stream>>>(row, col, w, cBase, bh, tmp, E, nbuck);
            bucket_deg_kernel<<<nbuck, BUCK_NODES, 0, stream>>>(tmp, cBase, x, dinv, xd, N);

            // layer 0 (one pass, all 3 stacks)
            layer0_kernel<<<nbuck, BUCK_NODES, 0, stream>>>(tmp, cBase, xd, x, dinv, initW,
                                                            rootW + 0 * KK, bias + 0 * KK,
                                                            zdA[0], zdA[1], zdA[2], N);
            // layers 1,2 (per-stack passes, ping-pong)
            for (int k = 0; k < KK; ++k)
                layer_pass_kernel<0><<<nbuck, BUCK_NODES, 0, stream>>>(
                    tmp, cBase, zdA[k], x, dinv, weight + 0 * KK + k, rootW + 1 * KK + k,
                    bias + 1 * KK + k, zdB[k], nullptr, nullptr, nullptr, nullptr, N);
            for (int k = 0; k < KK; ++k)
                layer_pass_kernel<0><<<nbuck, BUCK_NODES, 0, stream>>>(
                    tmp, cBase, zdB[k], x, dinv, weight + 1 * KK + k, rootW + 2 * KK + k,
                    bias + 2 * KK + k, zdA[k], nullptr, nullptr, nullptr, nullptr, N);
            // layer 3 fused with mean/linear/sigmoid
            layer_pass_kernel<1><<<nbuck, BUCK_NODES, 0, stream>>>(
                tmp, cBase, zdA[0], x, dinv, weight + 2 * KK + 0, rootW + 3 * KK + 0,
                bias + 3 * KK + 0, nullptr, part, nullptr, nullptr, nullptr, N);
            layer_pass_kernel<2><<<nbuck, BUCK_NODES, 0, stream>>>(
                tmp, cBase, zdA[1], x, dinv, weight + 2 * KK + 1, rootW + 3 * KK + 1,
                bias + 3 * KK + 1, nullptr, part, nullptr, nullptr, nullptr, N);
            layer_pass_kernel<3><<<nbuck, BUCK_NODES, 0, stream>>>(
                tmp, cBase, zdA[2], x, dinv, weight + 2 * KK + 2, rootW + 3 * KK + 2,
                bias + 3 * KK + 2, nullptr, part, lin_w, lin_b, outp, N);
            return;
        }
    }

    // ---- fallback: round-3 CSR-pull path ----
    {
        size_t off = 0;
        size_t pairsOff    = off; off += align16((size_t)E * 8);
        size_t posOff      = off; off += align16((size_t)E * 4);
        size_t stAOff      = off; off += align16((size_t)N * 16);
        size_t stBOff      = off; off += align16((size_t)N * 16);
        size_t dinvOff     = off; off += align16((size_t)N * 4);
        size_t cntOff      = off; off += align16((size_t)N * 4);
        size_t ptrOff      = off; off += align16((size_t)(N + 1) * 4);
        size_t partialsOff = off; off += align16((size_t)SCAN_BLOCK * 4);

        char* wsb = (char*)d_ws;
        float2* pairs = (float2*)(wsb + pairsOff);
        int*    pos   = (int*)(wsb + posOff);
        float4* stA   = (float4*)(wsb + stAOff);
        float4* stB   = (float4*)(wsb + stBOff);
        float*  dinv  = (float*)(wsb + dinvOff);
        int*    cnt   = (int*)(wsb + cntOff);
        int*    ptr   = (int*)(wsb + ptrOff);
        int*    parts = (int*)(wsb + partialsOff);

        hipMemsetAsync(cnt, 0, (size_t)N * 4, stream);

        count_pos_kernel<<<8192, TPB, 0, stream>>>(col, cnt, pos, E);
        scan1_kernel<<<nScanB, SCAN_BLOCK, 0, stream>>>(cnt, ptr, parts, N);
        scan2_kernel<<<1, SCAN_BLOCK, 0, stream>>>(parts, nScanB);
        scan3_kernel<<<nScanB, SCAN_BLOCK, 0, stream>>>(ptr, nullptr, parts, N, E);
        scatter2_kernel<<<8192, TPB, 0, stream>>>(row, col, w, ptr, pos, pairs, E);
        degsum_kernel<<<gridN, TPB, 0, stream>>>(ptr, pairs, dinv, N);
        fixup_kernel<<<8192, TPB, 0, stream>>>(pairs, dinv, E);

        pull0_kernel<<<gridN, TPB, 0, stream>>>(ptr, pairs, x, dinv, initW,
                                                rootW + 0 * KK, bias + 0 * KK, stA, N);
        pullv_kernel<<<gridN, TPB, 0, stream>>>(ptr, pairs, stA, x, dinv, weight + 0 * KK,
                                                rootW + 1 * KK, bias + 1 * KK, stB, N);
        pullv_kernel<<<gridN, TPB, 0, stream>>>(ptr, pairs, stB, x, dinv, weight + 1 * KK,
                                                rootW + 2 * KK, bias + 2 * KK, stA, N);
        pull_final_kernel<<<gridN, TPB, 0, stream>>>(ptr, pairs, stA, x, dinv, weight + 2 * KK,
                                                     rootW + 3 * KK, bias + 3 * KK,
                                                     lin_w, lin_b, outp, N);
    }
}